// Round 4
// baseline (666.711 us; speedup 1.0000x reference)
//
#include <hip/hip_runtime.h>
#include <hip/hip_bf16.h>

// Problem constants
#define B_  2
#define S_  2048
#define D_  1024
#define H_  16
#define HD_ 64
#define M_  4096   // B_*S_

// ALL inputs/outputs are FLOAT32 (per reference: jnp.float32 everywhere).
// Internal compute: bf16 MFMA with f32 accumulation (2%-of-max threshold allows it).
//
// Workspace (24 MB + 45 KB):
//   ws[0,8)MB   : q  bf16 [4096][1024]  (q -> q2 -> attn_out, in-place)
//   ws[8,16)MB  : kb bf16 [4096][1024]
//   ws[16,24)MB : vb bf16 [4096][1024]
//   ws+24MB     : biasf f32 [3][1024], then mean f32 [4096], rstd f32 [4096]

typedef __attribute__((ext_vector_type(8))) short short8;
typedef __attribute__((ext_vector_type(4))) float f32x4;

static __device__ __forceinline__ float bf2f(unsigned short h){
  union{unsigned u; float f;} c; c.u = ((unsigned)h)<<16; return c.f;
}
static __device__ __forceinline__ unsigned short f2bf(float f){
  union{float f; unsigned u;} c; c.f = f;
  unsigned u = c.u;
  return (unsigned short)((u + 0x7fffu + ((u>>16)&1u)) >> 16);  // RNE
}

// ---------------------------------------------------------------------------
// Per-row LN stats of data (f32): mean[row], rstd[row]. One wave per row.
// ---------------------------------------------------------------------------
__global__ __launch_bounds__(256) void stats_kernel(const float* __restrict__ x,
                                                    float* __restrict__ mean,
                                                    float* __restrict__ rstd){
  int row = blockIdx.x*4 + (threadIdx.x>>6);
  int l = threadIdx.x & 63;
  const float4* xr = (const float4*)(x + (size_t)row*D_);
  float s = 0.f, ss = 0.f;
  #pragma unroll
  for (int i=0;i<4;i++){
    float4 v = xr[l + 64*i];
    s  += v.x+v.y+v.z+v.w;
    ss += v.x*v.x+v.y*v.y+v.z*v.z+v.w*v.w;
  }
  #pragma unroll
  for (int m=1;m<64;m<<=1){ s += __shfl_xor(s, m, 64); ss += __shfl_xor(ss, m, 64); }
  if (l==0){
    float me = s*(1.0f/D_);
    float var = ss*(1.0f/D_) - me*me;
    mean[row] = me;
    rstd[row] = rsqrtf(var + 1e-5f);
  }
}

// ---------------------------------------------------------------------------
// Folded bias: biasf[z][n] = bp_z[n] + sum_k bln_z[k] * W_z[k][n]   (all f32)
// grid (16, 3): 64 n per block, 4-way k split. z: 0=q,1=k,2=v.
// ---------------------------------------------------------------------------
__global__ __launch_bounds__(256) void biasfold_kernel(
  const float* __restrict__ Wq, const float* __restrict__ Wk, const float* __restrict__ Wv,
  const float* __restrict__ blq, const float* __restrict__ blk, const float* __restrict__ blv,
  const float* __restrict__ bpq, const float* __restrict__ bpk, const float* __restrict__ bpv,
  float* __restrict__ bf){
  int z = blockIdx.y;
  const float* W  = (z==0)?Wq:(z==1)?Wk:Wv;
  const float* bl = (z==0)?blq:(z==1)?blk:blv;
  const float* bp = (z==0)?bpq:(z==1)?bpk:bpv;
  int nl = threadIdx.x & 63, kg = threadIdx.x >> 6;
  int n = blockIdx.x*64 + nl;
  float acc = 0.f;
  for (int k = kg*256; k < (kg+1)*256; k++)
    acc += bl[k] * W[(size_t)k*D_ + n];
  __shared__ float red[4][64];
  red[kg][nl] = acc;
  __syncthreads();
  if (threadIdx.x < 64){
    int nn = blockIdx.x*64 + threadIdx.x;
    bf[z*D_ + nn] = red[0][threadIdx.x]+red[1][threadIdx.x]+red[2][threadIdx.x]+red[3][threadIdx.x]
                    + bp[nn];
  }
}

// ---------------------------------------------------------------------------
// MFMA GEMM, 128x128 tile, 4 waves, 16x16x32 bf16, BK=32.
// MODE 0 (QKV): A = f32 data with on-the-fly LN (stats precomputed),
//               W = f32 [k][n] scaled by g[k], bias = biasf slice (f32),
//               C = bf16.
// MODE 1 (out-proj): A = bf16, W = f32 [k][n], bias = bo (f32), C = f32.
// W is transposed into LDS (Bs[n][k]) during staging.
// ---------------------------------------------------------------------------
template<int MODE>
__global__ __launch_bounds__(256) void gemm_kernel(
  const void* __restrict__ Ap,
  const float* __restrict__ W,
  const float* __restrict__ g,
  const float* __restrict__ biasv,
  const float* __restrict__ mean,
  const float* __restrict__ rstd,
  unsigned short* __restrict__ Cb,
  float* __restrict__ Cf)
{
  __shared__ __align__(16) unsigned short As[128*40];
  __shared__ __align__(16) unsigned short Bs[128*40];
  int tid = threadIdx.x, w = tid>>6, l = tid&63;
  int m0 = blockIdx.x*128, n0 = blockIdx.y*128;
  int wr = (w>>1)*64, wc = (w&1)*64;
  int lr = l&15, qd = l>>4;
  int srow = tid>>2, scol = (tid&3)*8;
  int kr = tid>>3, nc = (tid&7)*8;   // B staging: 32 k-rows x (8x16=128 cols)... see below

  // B staging mapping: kr in [0,32), each thread handles 16 cols at (tid&7)*16
  int nc16 = (tid&7)*16;

  float me0=0.f, rs0=1.f, me1=0.f, rs1=1.f;
  if (MODE==0){
    me0 = mean[m0+srow];    rs0 = rstd[m0+srow];
    me1 = mean[m0+srow+64]; rs1 = rstd[m0+srow+64];
  }

  const f32x4 fz = {0.f,0.f,0.f,0.f};
  f32x4 acc[4][4];
  #pragma unroll
  for (int i=0;i<4;i++)
    #pragma unroll
    for (int j=0;j<4;j++) acc[i][j] = fz;

  for (int kk=0; kk<D_; kk+=32){
    __syncthreads();
    // ---- A tile ----
    if (MODE==0){
      const float* A = (const float*)Ap;
      const float* p0 = A + (size_t)(m0+srow   )*D_ + kk + scol;
      const float* p1 = A + (size_t)(m0+srow+64)*D_ + kk + scol;
      float4 a0 = *(const float4*)(p0), a0b = *(const float4*)(p0+4);
      float4 a1 = *(const float4*)(p1), a1b = *(const float4*)(p1+4);
      union{uint4 v; unsigned short u[8];} o0, o1;
      o0.u[0]=f2bf((a0.x -me0)*rs0); o0.u[1]=f2bf((a0.y -me0)*rs0);
      o0.u[2]=f2bf((a0.z -me0)*rs0); o0.u[3]=f2bf((a0.w -me0)*rs0);
      o0.u[4]=f2bf((a0b.x-me0)*rs0); o0.u[5]=f2bf((a0b.y-me0)*rs0);
      o0.u[6]=f2bf((a0b.z-me0)*rs0); o0.u[7]=f2bf((a0b.w-me0)*rs0);
      o1.u[0]=f2bf((a1.x -me1)*rs1); o1.u[1]=f2bf((a1.y -me1)*rs1);
      o1.u[2]=f2bf((a1.z -me1)*rs1); o1.u[3]=f2bf((a1.w -me1)*rs1);
      o1.u[4]=f2bf((a1b.x-me1)*rs1); o1.u[5]=f2bf((a1b.y-me1)*rs1);
      o1.u[6]=f2bf((a1b.z-me1)*rs1); o1.u[7]=f2bf((a1b.w-me1)*rs1);
      *(uint4*)(As + srow*40      + scol) = o0.v;
      *(uint4*)(As + (srow+64)*40 + scol) = o1.v;
    } else {
      const unsigned short* A = (const unsigned short*)Ap;
      *(uint4*)(As + srow*40      + scol) = *(const uint4*)(A + (size_t)(m0+srow   )*D_ + kk + scol);
      *(uint4*)(As + (srow+64)*40 + scol) = *(const uint4*)(A + (size_t)(m0+srow+64)*D_ + kk + scol);
    }
    // ---- B tile: W[kk+kr][n0+nc16 .. +16) -> Bs[n][k] transposed ----
    {
      float gs = (MODE==0) ? g[kk+kr] : 1.0f;
      const float* src = W + (size_t)(kk+kr)*D_ + n0 + nc16;
      float4 w0 = *(const float4*)(src);
      float4 w1 = *(const float4*)(src+4);
      float4 w2 = *(const float4*)(src+8);
      float4 w3 = *(const float4*)(src+12);
      Bs[(nc16+ 0)*40+kr] = f2bf(w0.x*gs); Bs[(nc16+ 1)*40+kr] = f2bf(w0.y*gs);
      Bs[(nc16+ 2)*40+kr] = f2bf(w0.z*gs); Bs[(nc16+ 3)*40+kr] = f2bf(w0.w*gs);
      Bs[(nc16+ 4)*40+kr] = f2bf(w1.x*gs); Bs[(nc16+ 5)*40+kr] = f2bf(w1.y*gs);
      Bs[(nc16+ 6)*40+kr] = f2bf(w1.z*gs); Bs[(nc16+ 7)*40+kr] = f2bf(w1.w*gs);
      Bs[(nc16+ 8)*40+kr] = f2bf(w2.x*gs); Bs[(nc16+ 9)*40+kr] = f2bf(w2.y*gs);
      Bs[(nc16+10)*40+kr] = f2bf(w2.z*gs); Bs[(nc16+11)*40+kr] = f2bf(w2.w*gs);
      Bs[(nc16+12)*40+kr] = f2bf(w3.x*gs); Bs[(nc16+13)*40+kr] = f2bf(w3.y*gs);
      Bs[(nc16+14)*40+kr] = f2bf(w3.z*gs); Bs[(nc16+15)*40+kr] = f2bf(w3.w*gs);
    }
    __syncthreads();
    short8 af[4], bfr[4];
    #pragma unroll
    for (int i=0;i<4;i++) af[i]  = *(const short8*)(As + (wr + i*16 + lr)*40 + qd*8);
    #pragma unroll
    for (int j=0;j<4;j++) bfr[j] = *(const short8*)(Bs + (wc + j*16 + lr)*40 + qd*8);
    #pragma unroll
    for (int i=0;i<4;i++)
      #pragma unroll
      for (int j=0;j<4;j++)
        acc[i][j] = __builtin_amdgcn_mfma_f32_16x16x32_bf16(af[i], bfr[j], acc[i][j], 0, 0, 0);
  }

  #pragma unroll
  for (int j=0;j<4;j++){
    int n = n0 + wc + j*16 + lr;
    float bias = biasv[n];
    #pragma unroll
    for (int i=0;i<4;i++){
      int mb = m0 + wr + i*16 + qd*4;
      if (MODE==0){
        Cb[(size_t)(mb+0)*D_ + n] = f2bf(acc[i][j][0] + bias);
        Cb[(size_t)(mb+1)*D_ + n] = f2bf(acc[i][j][1] + bias);
        Cb[(size_t)(mb+2)*D_ + n] = f2bf(acc[i][j][2] + bias);
        Cb[(size_t)(mb+3)*D_ + n] = f2bf(acc[i][j][3] + bias);
      } else {
        Cf[(size_t)(mb+0)*D_ + n] = acc[i][j][0] + bias;
        Cf[(size_t)(mb+1)*D_ + n] = acc[i][j][1] + bias;
        Cf[(size_t)(mb+2)*D_ + n] = acc[i][j][2] + bias;
        Cf[(size_t)(mb+3)*D_ + n] = acc[i][j][3] + bias;
      }
    }
  }
}

// ---------------------------------------------------------------------------
// Flash attention pass, IN-PLACE on QO (bf16): QO_rows = softmax(scl*Q K^T) V.
// K,V row-major bf16 [4096][1024], head slice at h*64. V transposed in LDS.
// Block (qt,bh) reads only its own 64 q-rows (into sQ first) and writes
// exactly those cells at the end -> in-place safe.
// ---------------------------------------------------------------------------
__global__ __launch_bounds__(256) void attn_kernel(
  unsigned short* __restrict__ QO,
  const unsigned short* __restrict__ K,
  const unsigned short* __restrict__ V)
{
  int qt = blockIdx.x, bh = blockIdx.y;
  int b = bh >> 4, h = bh & 15;
  int tid = threadIdx.x, w = tid>>6, l = tid&63;
  int lr = l&15, qd = l>>4;
  __shared__ __align__(16) unsigned short sQ[64*72];
  __shared__ __align__(16) unsigned short sK[64*72];
  __shared__ __align__(16) unsigned short sVT[64*72];  // [d][s]
  __shared__ __align__(16) unsigned short sP[4][16*72];
  int r8 = tid>>3, c8 = (tid&7)*8;

  unsigned short* Qb = QO + (size_t)(b*S_ + qt*64)*D_ + h*HD_;
  *(uint4*)(sQ + r8*72      + c8) = *(const uint4*)(Qb + (size_t)r8*D_      + c8);
  *(uint4*)(sQ + (r8+32)*72 + c8) = *(const uint4*)(Qb + (size_t)(r8+32)*D_ + c8);
  __syncthreads();
  short8 qf0 = *(const short8*)(sQ + (w*16+lr)*72      + qd*8);
  short8 qf1 = *(const short8*)(sQ + (w*16+lr)*72 + 32 + qd*8);

  float m_i[4] = {-1e30f,-1e30f,-1e30f,-1e30f};
  float l_i[4] = {0.f,0.f,0.f,0.f};
  const f32x4 fz = {0.f,0.f,0.f,0.f};
  f32x4 oacc[4];
  #pragma unroll
  for (int t=0;t<4;t++) oacc[t] = fz;

  const unsigned short* Kb = K + (size_t)(b*S_)*D_ + h*HD_;
  const unsigned short* Vb = V + (size_t)(b*S_)*D_ + h*HD_;
  const float SCL = 0.125f;               // 1/sqrt(64)
  const float L2E = 1.44269504088896340736f;

  for (int kt = 0; kt < S_; kt += 64){
    __syncthreads();
    {
      const unsigned short* Kr = Kb + (size_t)(kt+r8)*D_ + c8;
      *(uint4*)(sK + r8*72      + c8) = *(const uint4*)(Kr);
      *(uint4*)(sK + (r8+32)*72 + c8) = *(const uint4*)(Kr + (size_t)32*D_);
      const unsigned short* Vr = Vb + (size_t)(kt+r8)*D_ + c8;
      union{uint4 v; unsigned short u[8];} v0, v1;
      v0.v = *(const uint4*)(Vr);
      v1.v = *(const uint4*)(Vr + (size_t)32*D_);
      #pragma unroll
      for (int i=0;i<8;i++){
        sVT[(c8+i)*72 + r8     ] = v0.u[i];
        sVT[(c8+i)*72 + r8 + 32] = v1.u[i];
      }
    }
    __syncthreads();

    f32x4 sc[4];
    #pragma unroll
    for (int t=0;t<4;t++){
      short8 kf0 = *(const short8*)(sK + (t*16+lr)*72      + qd*8);
      short8 kf1 = *(const short8*)(sK + (t*16+lr)*72 + 32 + qd*8);
      f32x4 z4 = fz;
      z4 = __builtin_amdgcn_mfma_f32_16x16x32_bf16(qf0, kf0, z4, 0,0,0);
      z4 = __builtin_amdgcn_mfma_f32_16x16x32_bf16(qf1, kf1, z4, 0,0,0);
      sc[t] = z4;
    }
    #pragma unroll
    for (int t=0;t<4;t++){ sc[t][0]*=SCL; sc[t][1]*=SCL; sc[t][2]*=SCL; sc[t][3]*=SCL; }

    float alpha[4];
    #pragma unroll
    for (int r=0;r<4;r++){
      float mx = fmaxf(fmaxf(sc[0][r], sc[1][r]), fmaxf(sc[2][r], sc[3][r]));
      #pragma unroll
      for (int msk=1; msk<16; msk<<=1) mx = fmaxf(mx, __shfl_xor(mx, msk, 64));
      float mn = fmaxf(m_i[r], mx);
      alpha[r] = exp2f((m_i[r]-mn)*L2E);
      m_i[r] = mn;
      float ps = 0.f;
      #pragma unroll
      for (int t=0;t<4;t++){
        float p = exp2f((sc[t][r]-mn)*L2E);
        sc[t][r] = p;
        ps += p;
      }
      #pragma unroll
      for (int msk=1; msk<16; msk<<=1) ps += __shfl_xor(ps, msk, 64);
      l_i[r] = l_i[r]*alpha[r] + ps;
    }
    #pragma unroll
    for (int t=0;t<4;t++){
      oacc[t][0]*=alpha[0]; oacc[t][1]*=alpha[1]; oacc[t][2]*=alpha[2]; oacc[t][3]*=alpha[3];
    }

    unsigned short* Pw = &sP[w][0];
    #pragma unroll
    for (int t=0;t<4;t++)
      #pragma unroll
      for (int r=0;r<4;r++)
        Pw[(qd*4+r)*72 + t*16 + lr] = f2bf(sc[t][r]);
    short8 pf0 = *(const short8*)(Pw + lr*72      + qd*8);
    short8 pf1 = *(const short8*)(Pw + lr*72 + 32 + qd*8);

    #pragma unroll
    for (int t=0;t<4;t++){
      short8 vf0 = *(const short8*)(sVT + (t*16+lr)*72      + qd*8);
      short8 vf1 = *(const short8*)(sVT + (t*16+lr)*72 + 32 + qd*8);
      oacc[t] = __builtin_amdgcn_mfma_f32_16x16x32_bf16(pf0, vf0, oacc[t], 0,0,0);
      oacc[t] = __builtin_amdgcn_mfma_f32_16x16x32_bf16(pf1, vf1, oacc[t], 0,0,0);
    }
  }

  float inv[4];
  #pragma unroll
  for (int r=0;r<4;r++) inv[r] = 1.0f/l_i[r];
  #pragma unroll
  for (int t=0;t<4;t++)
    #pragma unroll
    for (int r=0;r<4;r++)
      Qb[(size_t)(w*16 + qd*4 + r)*D_ + t*16 + lr] = f2bf(oacc[t][r]*inv[r]);
}

// ---------------------------------------------------------------------------
extern "C" void kernel_launch(void* const* d_in, const int* in_sizes, int n_in,
                              void* d_out, int out_size, void* d_ws, size_t ws_size,
                              hipStream_t stream){
  const float* data = (const float*)d_in[0];
  const float* g_k  = (const float*)d_in[1];
  const float* b_k  = (const float*)d_in[2];
  const float* g_q  = (const float*)d_in[3];
  const float* b_q  = (const float*)d_in[4];
  const float* g_v  = (const float*)d_in[5];
  const float* b_v  = (const float*)d_in[6];
  const float* Wq   = (const float*)d_in[7];
  const float* bq   = (const float*)d_in[8];
  const float* Wk   = (const float*)d_in[9];
  const float* bk   = (const float*)d_in[10];
  const float* Wv   = (const float*)d_in[11];
  const float* bv   = (const float*)d_in[12];
  const float* Wo   = (const float*)d_in[13];
  const float* bo   = (const float*)d_in[14];
  float* out = (float*)d_out;

  char* ws = (char*)d_ws;
  const size_t MB = (size_t)1<<20;
  unsigned short* q    = (unsigned short*)(ws);           // [0,8) MB bf16
  unsigned short* kb   = (unsigned short*)(ws + 8*MB);    // [8,16) MB bf16
  unsigned short* vb   = (unsigned short*)(ws + 16*MB);   // [16,24) MB bf16
  float*          bfld = (float*)(ws + 24*MB);            // 3*1024 f32
  float*          mean = bfld + 3*D_;                     // 4096 f32
  float*          rstd = mean + M_;                       // 4096 f32

  dim3 gg(32, 8), gb(256);
  stats_kernel<<<dim3(M_/4), gb, 0, stream>>>(data, mean, rstd);
  biasfold_kernel<<<dim3(16,3), gb, 0, stream>>>(Wq,Wk,Wv, b_q,b_k,b_v, bq,bk,bv, bfld);
  // QKV projections: LN + gamma folded, bf16 outputs
  gemm_kernel<0><<<gg, gb, 0, stream>>>(data, Wq, g_q, bfld + 0*D_, mean, rstd, q,  (float*)0);
  gemm_kernel<0><<<gg, gb, 0, stream>>>(data, Wk, g_k, bfld + 1*D_, mean, rstd, kb, (float*)0);
  gemm_kernel<0><<<gg, gb, 0, stream>>>(data, Wv, g_v, bfld + 2*D_, mean, rstd, vb, (float*)0);
  // Hopfield: q <- softmax(b q K^T) K ; then out_h <- softmax(b q K^T) V
  attn_kernel<<<dim3(S_/64, B_*H_), gb, 0, stream>>>(q, kb, kb);
  attn_kernel<<<dim3(S_/64, B_*H_), gb, 0, stream>>>(q, kb, vb);
  // Out-projection: f32 result straight to d_out
  gemm_kernel<1><<<gg, gb, 0, stream>>>(q, Wo, (const float*)0, bo,
                                        (const float*)0, (const float*)0,
                                        (unsigned short*)0, out);
}

// Round 5
// 513.010 us; speedup vs baseline: 1.2996x; 1.2996x over previous
//
#include <hip/hip_runtime.h>
#include <hip/hip_bf16.h>

// Problem constants
#define B_  2
#define S_  2048
#define D_  1024
#define H_  16
#define HD_ 64
#define M_  4096   // B_*S_

// Inputs/outputs f32; internal compute bf16 MFMA with f32 accumulation.
//
// Workspace (24 MB + 45 KB, proven size):
//   ws[0,8)MB   : q  bf16 [4096][1024]  (q -> attn out, in-place)
//   ws[8,16)MB  : kb bf16 [4096][1024]
//   ws[16,24)MB : kT bf16 [32][64][2048]  ([bh][d][s])
//   ws+24MB     : biasf f32 [3][1024], mean f32 [4096], rstd f32 [4096]
// vT bf16 [32][64][2048] lives in d_out[0,8)MB (d_out is 16MB f32; vT dead
// before the out-projection overwrites d_out).

typedef __attribute__((ext_vector_type(8))) short short8;
typedef __attribute__((ext_vector_type(4))) float f32x4;

static __device__ __forceinline__ float bf2f(unsigned short h){
  union{unsigned u; float f;} c; c.u = ((unsigned)h)<<16; return c.f;
}
static __device__ __forceinline__ unsigned short f2bf(float f){
  union{float f; unsigned u;} c; c.f = f;
  unsigned u = c.u;
  return (unsigned short)((u + 0x7fffu + ((u>>16)&1u)) >> 16);  // RNE
}

// ---------------------------------------------------------------------------
// Per-row LN stats of data (f32): mean[row], rstd[row]. One wave per row.
// ---------------------------------------------------------------------------
__global__ __launch_bounds__(256) void stats_kernel(const float* __restrict__ x,
                                                    float* __restrict__ mean,
                                                    float* __restrict__ rstd){
  int row = blockIdx.x*4 + (threadIdx.x>>6);
  int l = threadIdx.x & 63;
  const float4* xr = (const float4*)(x + (size_t)row*D_);
  float s = 0.f, ss = 0.f;
  #pragma unroll
  for (int i=0;i<4;i++){
    float4 v = xr[l + 64*i];
    s  += v.x+v.y+v.z+v.w;
    ss += v.x*v.x+v.y*v.y+v.z*v.z+v.w*v.w;
  }
  #pragma unroll
  for (int m=1;m<64;m<<=1){ s += __shfl_xor(s, m, 64); ss += __shfl_xor(ss, m, 64); }
  if (l==0){
    float me = s*(1.0f/D_);
    float var = ss*(1.0f/D_) - me*me;
    mean[row] = me;
    rstd[row] = rsqrtf(var + 1e-5f);
  }
}

// ---------------------------------------------------------------------------
// Folded bias: biasf[z][n] = bp_z[n] + sum_k bln_z[k] * W_z[k][n]   (all f32)
// ---------------------------------------------------------------------------
__global__ __launch_bounds__(256) void biasfold_kernel(
  const float* __restrict__ Wq, const float* __restrict__ Wk, const float* __restrict__ Wv,
  const float* __restrict__ blq, const float* __restrict__ blk, const float* __restrict__ blv,
  const float* __restrict__ bpq, const float* __restrict__ bpk, const float* __restrict__ bpv,
  float* __restrict__ bf){
  int z = blockIdx.y;
  const float* W  = (z==0)?Wq:(z==1)?Wk:Wv;
  const float* bl = (z==0)?blq:(z==1)?blk:blv;
  const float* bp = (z==0)?bpq:(z==1)?bpk:bpv;
  int nl = threadIdx.x & 63, kg = threadIdx.x >> 6;
  int n = blockIdx.x*64 + nl;
  float acc = 0.f;
  for (int k = kg*256; k < (kg+1)*256; k++)
    acc += bl[k] * W[(size_t)k*D_ + n];
  __shared__ float red[4][64];
  red[kg][nl] = acc;
  __syncthreads();
  if (threadIdx.x < 64){
    int nn = blockIdx.x*64 + threadIdx.x;
    bf[z*D_ + nn] = red[0][threadIdx.x]+red[1][threadIdx.x]+red[2][threadIdx.x]+red[3][threadIdx.x]
                    + bp[nn];
  }
}

// ---------------------------------------------------------------------------
// MFMA GEMM, 128x128 tile, 4 waves, 16x16x32 bf16, BK=32.
// MODE 0 (QKV): A = f32 data with on-the-fly LN, W = f32 [k][n] scaled by g,
//               bias = biasf slice. Outputs: oN row-major bf16 [4096][1024]
//               and/or oT per-head transposed bf16 [bh][d][s]. Either may be 0.
// MODE 1 (out-proj): A = bf16 [4096][1024], bias = bo, C = f32 -> Cf.
// ---------------------------------------------------------------------------
template<int MODE>
__global__ __launch_bounds__(256) void gemm_kernel(
  const void* __restrict__ Ap,
  const float* __restrict__ W,
  const float* __restrict__ g,
  const float* __restrict__ biasv,
  const float* __restrict__ mean,
  const float* __restrict__ rstd,
  unsigned short* __restrict__ oN,
  unsigned short* __restrict__ oT,
  float* __restrict__ Cf)
{
  __shared__ __align__(16) unsigned short As[128*40];
  __shared__ __align__(16) unsigned short Bs[128*40];
  int tid = threadIdx.x, w = tid>>6, l = tid&63;
  int m0 = blockIdx.x*128, n0 = blockIdx.y*128;
  int wr = (w>>1)*64, wc = (w&1)*64;
  int lr = l&15, qd = l>>4;
  int srow = tid>>2, scol = (tid&3)*8;
  int kr = tid>>3;
  int nc16 = (tid&7)*16;

  float me0=0.f, rs0=1.f, me1=0.f, rs1=1.f;
  if (MODE==0){
    me0 = mean[m0+srow];    rs0 = rstd[m0+srow];
    me1 = mean[m0+srow+64]; rs1 = rstd[m0+srow+64];
  }

  const f32x4 fz = {0.f,0.f,0.f,0.f};
  f32x4 acc[4][4];
  #pragma unroll
  for (int i=0;i<4;i++)
    #pragma unroll
    for (int j=0;j<4;j++) acc[i][j] = fz;

  for (int kk=0; kk<D_; kk+=32){
    __syncthreads();
    if (MODE==0){
      const float* A = (const float*)Ap;
      const float* p0 = A + (size_t)(m0+srow   )*D_ + kk + scol;
      const float* p1 = A + (size_t)(m0+srow+64)*D_ + kk + scol;
      float4 a0 = *(const float4*)(p0), a0b = *(const float4*)(p0+4);
      float4 a1 = *(const float4*)(p1), a1b = *(const float4*)(p1+4);
      union{uint4 v; unsigned short u[8];} o0, o1;
      o0.u[0]=f2bf((a0.x -me0)*rs0); o0.u[1]=f2bf((a0.y -me0)*rs0);
      o0.u[2]=f2bf((a0.z -me0)*rs0); o0.u[3]=f2bf((a0.w -me0)*rs0);
      o0.u[4]=f2bf((a0b.x-me0)*rs0); o0.u[5]=f2bf((a0b.y-me0)*rs0);
      o0.u[6]=f2bf((a0b.z-me0)*rs0); o0.u[7]=f2bf((a0b.w-me0)*rs0);
      o1.u[0]=f2bf((a1.x -me1)*rs1); o1.u[1]=f2bf((a1.y -me1)*rs1);
      o1.u[2]=f2bf((a1.z -me1)*rs1); o1.u[3]=f2bf((a1.w -me1)*rs1);
      o1.u[4]=f2bf((a1b.x-me1)*rs1); o1.u[5]=f2bf((a1b.y-me1)*rs1);
      o1.u[6]=f2bf((a1b.z-me1)*rs1); o1.u[7]=f2bf((a1b.w-me1)*rs1);
      *(uint4*)(As + srow*40      + scol) = o0.v;
      *(uint4*)(As + (srow+64)*40 + scol) = o1.v;
    } else {
      const unsigned short* A = (const unsigned short*)Ap;
      *(uint4*)(As + srow*40      + scol) = *(const uint4*)(A + (size_t)(m0+srow   )*D_ + kk + scol);
      *(uint4*)(As + (srow+64)*40 + scol) = *(const uint4*)(A + (size_t)(m0+srow+64)*D_ + kk + scol);
    }
    {
      float gs = (MODE==0) ? g[kk+kr] : 1.0f;
      const float* src = W + (size_t)(kk+kr)*D_ + n0 + nc16;
      float4 w0 = *(const float4*)(src);
      float4 w1 = *(const float4*)(src+4);
      float4 w2 = *(const float4*)(src+8);
      float4 w3 = *(const float4*)(src+12);
      Bs[(nc16+ 0)*40+kr] = f2bf(w0.x*gs); Bs[(nc16+ 1)*40+kr] = f2bf(w0.y*gs);
      Bs[(nc16+ 2)*40+kr] = f2bf(w0.z*gs); Bs[(nc16+ 3)*40+kr] = f2bf(w0.w*gs);
      Bs[(nc16+ 4)*40+kr] = f2bf(w1.x*gs); Bs[(nc16+ 5)*40+kr] = f2bf(w1.y*gs);
      Bs[(nc16+ 6)*40+kr] = f2bf(w1.z*gs); Bs[(nc16+ 7)*40+kr] = f2bf(w1.w*gs);
      Bs[(nc16+ 8)*40+kr] = f2bf(w2.x*gs); Bs[(nc16+ 9)*40+kr] = f2bf(w2.y*gs);
      Bs[(nc16+10)*40+kr] = f2bf(w2.z*gs); Bs[(nc16+11)*40+kr] = f2bf(w2.w*gs);
      Bs[(nc16+12)*40+kr] = f2bf(w3.x*gs); Bs[(nc16+13)*40+kr] = f2bf(w3.y*gs);
      Bs[(nc16+14)*40+kr] = f2bf(w3.z*gs); Bs[(nc16+15)*40+kr] = f2bf(w3.w*gs);
    }
    __syncthreads();
    short8 af[4], bfr[4];
    #pragma unroll
    for (int i=0;i<4;i++) af[i]  = *(const short8*)(As + (wr + i*16 + lr)*40 + qd*8);
    #pragma unroll
    for (int j=0;j<4;j++) bfr[j] = *(const short8*)(Bs + (wc + j*16 + lr)*40 + qd*8);
    #pragma unroll
    for (int i=0;i<4;i++)
      #pragma unroll
      for (int j=0;j<4;j++)
        acc[i][j] = __builtin_amdgcn_mfma_f32_16x16x32_bf16(af[i], bfr[j], acc[i][j], 0, 0, 0);
  }

  #pragma unroll
  for (int j=0;j<4;j++){
    int n = n0 + wc + j*16 + lr;
    float bias = biasv[n];
    #pragma unroll
    for (int i=0;i<4;i++){
      int mb = m0 + wr + i*16 + qd*4;
      float v0 = acc[i][j][0] + bias;
      float v1 = acc[i][j][1] + bias;
      float v2 = acc[i][j][2] + bias;
      float v3 = acc[i][j][3] + bias;
      if (MODE==0){
        if (oN){
          oN[(size_t)(mb+0)*D_ + n] = f2bf(v0);
          oN[(size_t)(mb+1)*D_ + n] = f2bf(v1);
          oN[(size_t)(mb+2)*D_ + n] = f2bf(v2);
          oN[(size_t)(mb+3)*D_ + n] = f2bf(v3);
        }
        if (oT){
          // [bh][d][s]: 4 acc regs = 4 consecutive tokens -> one 8B store
          int bb = mb >> 11, sI = mb & (S_-1);
          int hh = n >> 6,  dd = n & 63;
          ushort4 pk = make_ushort4(f2bf(v0), f2bf(v1), f2bf(v2), f2bf(v3));
          *(ushort4*)(oT + (size_t)((bb*H_ + hh)*HD_ + dd)*S_ + sI) = pk;
        }
      } else {
        Cf[(size_t)(mb+0)*D_ + n] = v0;
        Cf[(size_t)(mb+1)*D_ + n] = v1;
        Cf[(size_t)(mb+2)*D_ + n] = v2;
        Cf[(size_t)(mb+3)*D_ + n] = v3;
      }
    }
  }
}

// ---------------------------------------------------------------------------
// Fused double Hopfield attention, IN-PLACE on QO (bf16 [4096][1024]):
//   phase 0: q2 = softmax(b q K^T) K      (V := K, via KT [bh][d][s])
//   phase 1: out = softmax(b q2 K^T) V    (via VT [bh][d][s])
// Fixed-max softmax (scores bounded ~|q||k|/8 <= ~3.3 by Cauchy-Schwarz on
// LN'd rows): no running max / rescale; row-sum accumulated in C-layout,
// reduced once per phase. Block = 128 q-rows x 1 head; 4 waves x 32 rows.
// Block reads only its own q cells (rows qt*128.., cols h*64..) before
// writing exactly those cells -> in-place safe.
// ---------------------------------------------------------------------------
__global__ __launch_bounds__(256) void attn_fused(
  unsigned short* __restrict__ QO,
  const unsigned short* __restrict__ K,
  const unsigned short* __restrict__ KT,
  const unsigned short* __restrict__ VT)
{
  int qt = blockIdx.x;           // 0..31 (128-row tile, global m)
  int h  = blockIdx.y;           // 0..15
  int b  = qt >> 4;
  int bh = b*H_ + h;
  int tid = threadIdx.x, w = tid>>6, l = tid&63;
  int lr = l&15, qd = l>>4;
  int r8 = tid>>3, c8 = (tid&7)*8;
  int chf = c8>>5, co = c8&31;

  __shared__ __align__(16) unsigned short sK[2][64*40];   // [d-half][key][d%32]
  __shared__ __align__(16) unsigned short sV[2][64*40];   // [key-half][d][key%32]
  __shared__ __align__(16) unsigned short sP[4][2][32*40];// per-wave [key-half][qrow][key%32]

  const float CE = 0.125f * 1.44269504088896340736f;  // beta * log2(e)
  const f32x4 fz = {0.f,0.f,0.f,0.f};

  // Q fragments direct from global (rows w*32 + g*16 + lr of this tile)
  unsigned short* Qbase = QO + (size_t)(qt*128 + w*32)*D_ + h*64;
  short8 qf[2][2];
  #pragma unroll
  for (int gg=0; gg<2; gg++)
    #pragma unroll
    for (int hf=0; hf<2; hf++)
      qf[gg][hf] = *(const short8*)(Qbase + (size_t)(gg*16+lr)*D_ + hf*32 + qd*8);

  const unsigned short* Khead = K + (size_t)(b*S_)*D_ + h*64;

  f32x4 oacc[2][4], lac[2];

  #pragma unroll 1
  for (int phase=0; phase<2; phase++){
    const unsigned short* Vhead = (phase ? VT : KT) + (size_t)bh*HD_*S_;
    #pragma unroll
    for (int gg=0;gg<2;gg++){
      lac[gg]=fz;
      #pragma unroll
      for (int t=0;t<4;t++) oacc[gg][t]=fz;
    }

    for (int kt=0; kt<S_; kt+=64){
      __syncthreads();
      *(uint4*)(&sK[chf][(r8   )*40 + co]) = *(const uint4*)(Khead + (size_t)(kt+r8   )*D_ + c8);
      *(uint4*)(&sK[chf][(r8+32)*40 + co]) = *(const uint4*)(Khead + (size_t)(kt+r8+32)*D_ + c8);
      *(uint4*)(&sV[chf][(r8   )*40 + co]) = *(const uint4*)(Vhead + (size_t)(r8   )*S_ + kt + c8);
      *(uint4*)(&sV[chf][(r8+32)*40 + co]) = *(const uint4*)(Vhead + (size_t)(r8+32)*S_ + kt + c8);
      __syncthreads();

      // S strip: 32 q-rows x 64 keys per wave
      f32x4 sc[2][4];
      #pragma unroll
      for (int t=0;t<4;t++){
        short8 kf0 = *(const short8*)(&sK[0][(t*16+lr)*40 + qd*8]);
        short8 kf1 = *(const short8*)(&sK[1][(t*16+lr)*40 + qd*8]);
        #pragma unroll
        for (int gg=0;gg<2;gg++){
          f32x4 z = fz;
          z = __builtin_amdgcn_mfma_f32_16x16x32_bf16(qf[gg][0], kf0, z, 0,0,0);
          z = __builtin_amdgcn_mfma_f32_16x16x32_bf16(qf[gg][1], kf1, z, 0,0,0);
          sc[gg][t] = z;
        }
      }
      // exp (fixed max) + C-layout row-sum accumulate
      #pragma unroll
      for (int gg=0;gg<2;gg++)
        #pragma unroll
        for (int t=0;t<4;t++){
          f32x4 p;
          p[0]=exp2f(sc[gg][t][0]*CE); p[1]=exp2f(sc[gg][t][1]*CE);
          p[2]=exp2f(sc[gg][t][2]*CE); p[3]=exp2f(sc[gg][t][3]*CE);
          sc[gg][t]=p; lac[gg]+=p;
        }
      // P: C-layout -> A-frag via wave-private LDS
      #pragma unroll
      for (int gg=0;gg<2;gg++)
        #pragma unroll
        for (int t=0;t<4;t++){
          unsigned short* Ph = &sP[w][t>>1][0];
          int rowb = (gg*16+qd*4)*40 + (t&1)*16 + lr;
          Ph[rowb      ] = f2bf(sc[gg][t][0]);
          Ph[rowb +  40] = f2bf(sc[gg][t][1]);
          Ph[rowb +  80] = f2bf(sc[gg][t][2]);
          Ph[rowb + 120] = f2bf(sc[gg][t][3]);
        }
      short8 pf[2][2];
      #pragma unroll
      for (int gg=0;gg<2;gg++){
        pf[gg][0] = *(const short8*)(&sP[w][0][(gg*16+lr)*40 + qd*8]);
        pf[gg][1] = *(const short8*)(&sP[w][1][(gg*16+lr)*40 + qd*8]);
      }
      // O += P * V  (B = V^T rows from sV)
      #pragma unroll
      for (int t=0;t<4;t++){
        short8 vf0 = *(const short8*)(&sV[0][(t*16+lr)*40 + qd*8]);
        short8 vf1 = *(const short8*)(&sV[1][(t*16+lr)*40 + qd*8]);
        #pragma unroll
        for (int gg=0;gg<2;gg++){
          oacc[gg][t] = __builtin_amdgcn_mfma_f32_16x16x32_bf16(pf[gg][0], vf0, oacc[gg][t], 0,0,0);
          oacc[gg][t] = __builtin_amdgcn_mfma_f32_16x16x32_bf16(pf[gg][1], vf1, oacc[gg][t], 0,0,0);
        }
      }
    } // kt

    // reduce row-sums across the 16 lanes of each quad (key dim)
    #pragma unroll
    for (int gg=0;gg<2;gg++)
      #pragma unroll
      for (int msk=1; msk<16; msk<<=1){
        lac[gg][0] += __shfl_xor(lac[gg][0], msk, 64);
        lac[gg][1] += __shfl_xor(lac[gg][1], msk, 64);
        lac[gg][2] += __shfl_xor(lac[gg][2], msk, 64);
        lac[gg][3] += __shfl_xor(lac[gg][3], msk, 64);
      }

    if (phase==0){
      // q2 = O/l -> new Q fragments via the same LDS round-trip ([qrow][d])
      #pragma unroll
      for (int gg=0;gg<2;gg++){
        float i0=1.0f/lac[gg][0], i1=1.0f/lac[gg][1], i2=1.0f/lac[gg][2], i3=1.0f/lac[gg][3];
        #pragma unroll
        for (int t=0;t<4;t++){
          unsigned short* Ph = &sP[w][t>>1][0];
          int rowb = (gg*16+qd*4)*40 + (t&1)*16 + lr;
          Ph[rowb      ] = f2bf(oacc[gg][t][0]*i0);
          Ph[rowb +  40] = f2bf(oacc[gg][t][1]*i1);
          Ph[rowb +  80] = f2bf(oacc[gg][t][2]*i2);
          Ph[rowb + 120] = f2bf(oacc[gg][t][3]*i3);
        }
      }
      #pragma unroll
      for (int gg=0;gg<2;gg++){
        qf[gg][0] = *(const short8*)(&sP[w][0][(gg*16+lr)*40 + qd*8]);
        qf[gg][1] = *(const short8*)(&sP[w][1][(gg*16+lr)*40 + qd*8]);
      }
    } else {
      // final store (same cells this block read at start)
      #pragma unroll
      for (int gg=0;gg<2;gg++){
        float i0=1.0f/lac[gg][0], i1=1.0f/lac[gg][1], i2=1.0f/lac[gg][2], i3=1.0f/lac[gg][3];
        #pragma unroll
        for (int t=0;t<4;t++){
          size_t rb = (size_t)(qt*128 + w*32 + gg*16 + qd*4)*D_ + h*64 + t*16 + lr;
          QO[rb          ] = f2bf(oacc[gg][t][0]*i0);
          QO[rb +   (size_t)D_] = f2bf(oacc[gg][t][1]*i1);
          QO[rb + 2*(size_t)D_] = f2bf(oacc[gg][t][2]*i2);
          QO[rb + 3*(size_t)D_] = f2bf(oacc[gg][t][3]*i3);
        }
      }
    }
  } // phase
}

// ---------------------------------------------------------------------------
extern "C" void kernel_launch(void* const* d_in, const int* in_sizes, int n_in,
                              void* d_out, int out_size, void* d_ws, size_t ws_size,
                              hipStream_t stream){
  const float* data = (const float*)d_in[0];
  const float* g_k  = (const float*)d_in[1];
  const float* b_k  = (const float*)d_in[2];
  const float* g_q  = (const float*)d_in[3];
  const float* b_q  = (const float*)d_in[4];
  const float* g_v  = (const float*)d_in[5];
  const float* b_v  = (const float*)d_in[6];
  const float* Wq   = (const float*)d_in[7];
  const float* bq   = (const float*)d_in[8];
  const float* Wk   = (const float*)d_in[9];
  const float* bk   = (const float*)d_in[10];
  const float* Wv   = (const float*)d_in[11];
  const float* bv   = (const float*)d_in[12];
  const float* Wo   = (const float*)d_in[13];
  const float* bo   = (const float*)d_in[14];
  float* out = (float*)d_out;

  char* ws = (char*)d_ws;
  const size_t MB = (size_t)1<<20;
  unsigned short* q    = (unsigned short*)(ws);           // [0,8) MB
  unsigned short* kb   = (unsigned short*)(ws + 8*MB);    // [8,16) MB
  unsigned short* kT   = (unsigned short*)(ws + 16*MB);   // [16,24) MB
  float*          bfld = (float*)(ws + 24*MB);            // 3*1024 f32
  float*          mean = bfld + 3*D_;                     // 4096 f32
  float*          rstd = mean + M_;                       // 4096 f32
  unsigned short* vT   = (unsigned short*)d_out;          // first 8MB of d_out (dead before ogemm)

  dim3 gg(32, 8), gb(256);
  stats_kernel<<<dim3(M_/4), gb, 0, stream>>>(data, mean, rstd);
  biasfold_kernel<<<dim3(16,3), gb, 0, stream>>>(Wq,Wk,Wv, b_q,b_k,b_v, bq,bk,bv, bfld);
  gemm_kernel<0><<<gg, gb, 0, stream>>>(data, Wq, g_q, bfld + 0*D_, mean, rstd,
                                        q,  (unsigned short*)0, (float*)0);
  gemm_kernel<0><<<gg, gb, 0, stream>>>(data, Wk, g_k, bfld + 1*D_, mean, rstd,
                                        kb, kT, (float*)0);
  gemm_kernel<0><<<gg, gb, 0, stream>>>(data, Wv, g_v, bfld + 2*D_, mean, rstd,
                                        (unsigned short*)0, vT, (float*)0);
  attn_fused<<<dim3(32, H_), gb, 0, stream>>>(q, kb, kT, vT);
  gemm_kernel<1><<<gg, gb, 0, stream>>>(q, Wo, (const float*)0, bo,
                                        (const float*)0, (const float*)0,
                                        (unsigned short*)0, (unsigned short*)0, out);
}

// Round 6
// 387.662 us; speedup vs baseline: 1.7198x; 1.3233x over previous
//
#include <hip/hip_runtime.h>
#include <hip/hip_bf16.h>

// Problem constants
#define B_  2
#define S_  2048
#define D_  1024
#define H_  16
#define HD_ 64
#define M_  4096   // B_*S_

// Inputs/outputs f32; internal compute bf16 MFMA with f32 accumulation.
// Workspace (24 MB + 45 KB):
//   ws[0,8)MB   : q  bf16 [4096][1024]  (pre-scaled by beta*log2e; attn in-place)
//   ws[8,16)MB  : kb bf16 [4096][1024]
//   ws[16,24)MB : kT bf16 [32][64][2048]  ([bh][d][s])
//   ws+24MB     : biasf f32 [3][1024], mean f32 [4096], rstd f32 [4096]
// vT bf16 [32][64][2048] lives in d_out[0,8)MB (dead before out-projection).

typedef __attribute__((ext_vector_type(8))) short short8;
typedef __attribute__((ext_vector_type(4))) float f32x4;

#define CE_ 0.1803368801111204f   // 0.125 * log2(e)

static __device__ __forceinline__ unsigned short f2bfc(float f){
  union{float f; unsigned u;} c; c.f = f;
  return (unsigned short)((c.u + 0x8000u) >> 16);       // round-half-up, 2 ops
}
// pack two f32 -> two bf16 (round-half-up) in one b32: low=bf16(a), high=bf16(b)
static __device__ __forceinline__ unsigned pk2bf(float a, float b){
  union{float f; unsigned u;} ca, cb; ca.f=a; cb.f=b;
  return __builtin_amdgcn_perm(cb.u + 0x8000u, ca.u + 0x8000u, 0x07060302u);
}

// ---------------------------------------------------------------------------
// Per-row LN stats of data (f32): mean[row], rstd[row]. One wave per row.
// ---------------------------------------------------------------------------
__global__ __launch_bounds__(256) void stats_kernel(const float* __restrict__ x,
                                                    float* __restrict__ mean,
                                                    float* __restrict__ rstd){
  int row = blockIdx.x*4 + (threadIdx.x>>6);
  int l = threadIdx.x & 63;
  const float4* xr = (const float4*)(x + (size_t)row*D_);
  float s = 0.f, ss = 0.f;
  #pragma unroll
  for (int i=0;i<4;i++){
    float4 v = xr[l + 64*i];
    s  += v.x+v.y+v.z+v.w;
    ss += v.x*v.x+v.y*v.y+v.z*v.z+v.w*v.w;
  }
  #pragma unroll
  for (int m=1;m<64;m<<=1){ s += __shfl_xor(s, m, 64); ss += __shfl_xor(ss, m, 64); }
  if (l==0){
    float me = s*(1.0f/D_);
    float var = ss*(1.0f/D_) - me*me;
    mean[row] = me;
    rstd[row] = rsqrtf(var + 1e-5f);
  }
}

// ---------------------------------------------------------------------------
// Folded bias: biasf[z][n] = bp_z[n] + sum_k bln_z[k] * W_z[k][n]   (all f32)
// ---------------------------------------------------------------------------
__global__ __launch_bounds__(256) void biasfold_kernel(
  const float* __restrict__ Wq, const float* __restrict__ Wk, const float* __restrict__ Wv,
  const float* __restrict__ blq, const float* __restrict__ blk, const float* __restrict__ blv,
  const float* __restrict__ bpq, const float* __restrict__ bpk, const float* __restrict__ bpv,
  float* __restrict__ bf){
  int z = blockIdx.y;
  const float* W  = (z==0)?Wq:(z==1)?Wk:Wv;
  const float* bl = (z==0)?blq:(z==1)?blk:blv;
  const float* bp = (z==0)?bpq:(z==1)?bpk:bpv;
  int nl = threadIdx.x & 63, kg = threadIdx.x >> 6;
  int n = blockIdx.x*64 + nl;
  float acc = 0.f;
  for (int k = kg*256; k < (kg+1)*256; k++)
    acc += bl[k] * W[(size_t)k*D_ + n];
  __shared__ float red[4][64];
  red[kg][nl] = acc;
  __syncthreads();
  if (threadIdx.x < 64){
    int nn = blockIdx.x*64 + threadIdx.x;
    bf[z*D_ + nn] = red[0][threadIdx.x]+red[1][threadIdx.x]+red[2][threadIdx.x]+red[3][threadIdx.x]
                    + bp[nn];
  }
}

// ---------------------------------------------------------------------------
// Fused QKV GEMM, grid (32,8,3): z picks {q,k,v}. 128x128 tile, 4 waves.
// A = f32 data, LN applied on the fly; W = f32 [k][n] scaled by g[k];
// bias = biasf[z]; q output (z==0) pre-scaled by CE_.
// Outputs: z0 -> q row-major; z1 -> kb row-major + kT [bh][d][s]; z2 -> vT.
// ---------------------------------------------------------------------------
__global__ __launch_bounds__(256) void gemm_qkv(
  const float* __restrict__ data,
  const float* __restrict__ Wq, const float* __restrict__ Wk, const float* __restrict__ Wv,
  const float* __restrict__ gq, const float* __restrict__ gk, const float* __restrict__ gv,
  const float* __restrict__ biasf,
  const float* __restrict__ mean, const float* __restrict__ rstd,
  unsigned short* __restrict__ qv, unsigned short* __restrict__ kb,
  unsigned short* __restrict__ kT, unsigned short* __restrict__ vT)
{
  int z = blockIdx.z;
  const float* W = (z==0)?Wq:(z==1)?Wk:Wv;
  const float* g = (z==0)?gq:(z==1)?gk:gv;
  const float* bias = biasf + z*D_;
  unsigned short* oN = (z==0)?qv:(z==1)?kb:(unsigned short*)0;
  unsigned short* oT = (z==0)?(unsigned short*)0:(z==1)?kT:vT;
  float osc = (z==0)? CE_ : 1.0f;

  __shared__ __align__(16) unsigned short As[128*40];
  __shared__ __align__(16) unsigned short Bs[128*40];
  int tid = threadIdx.x, w = tid>>6, l = tid&63;
  int m0 = blockIdx.x*128, n0 = blockIdx.y*128;
  int wr = (w>>1)*64, wc = (w&1)*64;
  int lr = l&15, qd = l>>4;
  int srow = tid>>2, scol = (tid&3)*8;
  int kr = tid>>3;
  int nc16 = (tid&7)*16;

  float me0 = mean[m0+srow],    rs0 = rstd[m0+srow];
  float me1 = mean[m0+srow+64], rs1 = rstd[m0+srow+64];

  const f32x4 fz = {0.f,0.f,0.f,0.f};
  f32x4 acc[4][4];
  #pragma unroll
  for (int i=0;i<4;i++)
    #pragma unroll
    for (int j=0;j<4;j++) acc[i][j] = fz;

  for (int kk=0; kk<D_; kk+=32){
    __syncthreads();
    { // A tile with LN, packed converts
      const float* p0 = data + (size_t)(m0+srow   )*D_ + kk + scol;
      const float* p1 = data + (size_t)(m0+srow+64)*D_ + kk + scol;
      float4 a0 = *(const float4*)(p0), a0b = *(const float4*)(p0+4);
      float4 a1 = *(const float4*)(p1), a1b = *(const float4*)(p1+4);
      uint4 o0, o1;
      o0.x = pk2bf((a0.x -me0)*rs0, (a0.y -me0)*rs0);
      o0.y = pk2bf((a0.z -me0)*rs0, (a0.w -me0)*rs0);
      o0.z = pk2bf((a0b.x-me0)*rs0, (a0b.y-me0)*rs0);
      o0.w = pk2bf((a0b.z-me0)*rs0, (a0b.w-me0)*rs0);
      o1.x = pk2bf((a1.x -me1)*rs1, (a1.y -me1)*rs1);
      o1.y = pk2bf((a1.z -me1)*rs1, (a1.w -me1)*rs1);
      o1.z = pk2bf((a1b.x-me1)*rs1, (a1b.y-me1)*rs1);
      o1.w = pk2bf((a1b.z-me1)*rs1, (a1b.w-me1)*rs1);
      *(uint4*)(As + srow*40      + scol) = o0;
      *(uint4*)(As + (srow+64)*40 + scol) = o1;
    }
    { // B tile: W[kk+kr][n0+nc16..+16) -> Bs[n][k] transposed, scaled by g
      float gs = g[kk+kr];
      const float* src = W + (size_t)(kk+kr)*D_ + n0 + nc16;
      float4 w0 = *(const float4*)(src);
      float4 w1 = *(const float4*)(src+4);
      float4 w2 = *(const float4*)(src+8);
      float4 w3 = *(const float4*)(src+12);
      Bs[(nc16+ 0)*40+kr] = f2bfc(w0.x*gs); Bs[(nc16+ 1)*40+kr] = f2bfc(w0.y*gs);
      Bs[(nc16+ 2)*40+kr] = f2bfc(w0.z*gs); Bs[(nc16+ 3)*40+kr] = f2bfc(w0.w*gs);
      Bs[(nc16+ 4)*40+kr] = f2bfc(w1.x*gs); Bs[(nc16+ 5)*40+kr] = f2bfc(w1.y*gs);
      Bs[(nc16+ 6)*40+kr] = f2bfc(w1.z*gs); Bs[(nc16+ 7)*40+kr] = f2bfc(w1.w*gs);
      Bs[(nc16+ 8)*40+kr] = f2bfc(w2.x*gs); Bs[(nc16+ 9)*40+kr] = f2bfc(w2.y*gs);
      Bs[(nc16+10)*40+kr] = f2bfc(w2.z*gs); Bs[(nc16+11)*40+kr] = f2bfc(w2.w*gs);
      Bs[(nc16+12)*40+kr] = f2bfc(w3.x*gs); Bs[(nc16+13)*40+kr] = f2bfc(w3.y*gs);
      Bs[(nc16+14)*40+kr] = f2bfc(w3.z*gs); Bs[(nc16+15)*40+kr] = f2bfc(w3.w*gs);
    }
    __syncthreads();
    short8 af[4], bfr[4];
    #pragma unroll
    for (int i=0;i<4;i++) af[i]  = *(const short8*)(As + (wr + i*16 + lr)*40 + qd*8);
    #pragma unroll
    for (int j=0;j<4;j++) bfr[j] = *(const short8*)(Bs + (wc + j*16 + lr)*40 + qd*8);
    #pragma unroll
    for (int i=0;i<4;i++)
      #pragma unroll
      for (int j=0;j<4;j++)
        acc[i][j] = __builtin_amdgcn_mfma_f32_16x16x32_bf16(af[i], bfr[j], acc[i][j], 0, 0, 0);
  }

  #pragma unroll
  for (int j=0;j<4;j++){
    int n = n0 + wc + j*16 + lr;
    float bias_n = bias[n];
    #pragma unroll
    for (int i=0;i<4;i++){
      int mb = m0 + wr + i*16 + qd*4;
      float v0 = (acc[i][j][0] + bias_n)*osc;
      float v1 = (acc[i][j][1] + bias_n)*osc;
      float v2 = (acc[i][j][2] + bias_n)*osc;
      float v3 = (acc[i][j][3] + bias_n)*osc;
      if (oN){
        oN[(size_t)(mb+0)*D_ + n] = f2bfc(v0);
        oN[(size_t)(mb+1)*D_ + n] = f2bfc(v1);
        oN[(size_t)(mb+2)*D_ + n] = f2bfc(v2);
        oN[(size_t)(mb+3)*D_ + n] = f2bfc(v3);
      }
      if (oT){
        int bb = mb >> 11, sI = mb & (S_-1);
        int hh = n >> 6,  dd = n & 63;
        uint2 pk; pk.x = pk2bf(v0, v1); pk.y = pk2bf(v2, v3);
        *(uint2*)(oT + (size_t)((bb*H_ + hh)*HD_ + dd)*S_ + sI) = pk;
      }
    }
  }
}

// ---------------------------------------------------------------------------
// Out-projection GEMM: C = A(bf16) @ Wo(f32) + bo, f32 out. 128x128 tile.
// ---------------------------------------------------------------------------
__global__ __launch_bounds__(256) void gemm_out(
  const unsigned short* __restrict__ A,
  const float* __restrict__ W,
  const float* __restrict__ bo,
  float* __restrict__ Cf)
{
  __shared__ __align__(16) unsigned short As[128*40];
  __shared__ __align__(16) unsigned short Bs[128*40];
  int tid = threadIdx.x, w = tid>>6, l = tid&63;
  int m0 = blockIdx.x*128, n0 = blockIdx.y*128;
  int wr = (w>>1)*64, wc = (w&1)*64;
  int lr = l&15, qd = l>>4;
  int srow = tid>>2, scol = (tid&3)*8;
  int kr = tid>>3;
  int nc16 = (tid&7)*16;

  const f32x4 fz = {0.f,0.f,0.f,0.f};
  f32x4 acc[4][4];
  #pragma unroll
  for (int i=0;i<4;i++)
    #pragma unroll
    for (int j=0;j<4;j++) acc[i][j] = fz;

  for (int kk=0; kk<D_; kk+=32){
    __syncthreads();
    *(uint4*)(As + srow*40      + scol) = *(const uint4*)(A + (size_t)(m0+srow   )*D_ + kk + scol);
    *(uint4*)(As + (srow+64)*40 + scol) = *(const uint4*)(A + (size_t)(m0+srow+64)*D_ + kk + scol);
    {
      const float* src = W + (size_t)(kk+kr)*D_ + n0 + nc16;
      float4 w0 = *(const float4*)(src);
      float4 w1 = *(const float4*)(src+4);
      float4 w2 = *(const float4*)(src+8);
      float4 w3 = *(const float4*)(src+12);
      Bs[(nc16+ 0)*40+kr] = f2bfc(w0.x); Bs[(nc16+ 1)*40+kr] = f2bfc(w0.y);
      Bs[(nc16+ 2)*40+kr] = f2bfc(w0.z); Bs[(nc16+ 3)*40+kr] = f2bfc(w0.w);
      Bs[(nc16+ 4)*40+kr] = f2bfc(w1.x); Bs[(nc16+ 5)*40+kr] = f2bfc(w1.y);
      Bs[(nc16+ 6)*40+kr] = f2bfc(w1.z); Bs[(nc16+ 7)*40+kr] = f2bfc(w1.w);
      Bs[(nc16+ 8)*40+kr] = f2bfc(w2.x); Bs[(nc16+ 9)*40+kr] = f2bfc(w2.y);
      Bs[(nc16+10)*40+kr] = f2bfc(w2.z); Bs[(nc16+11)*40+kr] = f2bfc(w2.w);
      Bs[(nc16+12)*40+kr] = f2bfc(w3.x); Bs[(nc16+13)*40+kr] = f2bfc(w3.y);
      Bs[(nc16+14)*40+kr] = f2bfc(w3.z); Bs[(nc16+15)*40+kr] = f2bfc(w3.w);
    }
    __syncthreads();
    short8 af[4], bfr[4];
    #pragma unroll
    for (int i=0;i<4;i++) af[i]  = *(const short8*)(As + (wr + i*16 + lr)*40 + qd*8);
    #pragma unroll
    for (int j=0;j<4;j++) bfr[j] = *(const short8*)(Bs + (wc + j*16 + lr)*40 + qd*8);
    #pragma unroll
    for (int i=0;i<4;i++)
      #pragma unroll
      for (int j=0;j<4;j++)
        acc[i][j] = __builtin_amdgcn_mfma_f32_16x16x32_bf16(af[i], bfr[j], acc[i][j], 0, 0, 0);
  }

  #pragma unroll
  for (int j=0;j<4;j++){
    int n = n0 + wc + j*16 + lr;
    float bias_n = bo[n];
    #pragma unroll
    for (int i=0;i<4;i++){
      int mb = m0 + wr + i*16 + qd*4;
      Cf[(size_t)(mb+0)*D_ + n] = acc[i][j][0] + bias_n;
      Cf[(size_t)(mb+1)*D_ + n] = acc[i][j][1] + bias_n;
      Cf[(size_t)(mb+2)*D_ + n] = acc[i][j][2] + bias_n;
      Cf[(size_t)(mb+3)*D_ + n] = acc[i][j][3] + bias_n;
    }
  }
}

// ---------------------------------------------------------------------------
// Fused double Hopfield attention, TRANSPOSED compute (S^T / O^T), in-place
// on QO (bf16 [4096][1024], pre-scaled by CE_):
//   phase 0: q2 = softmax-from-exp2(q K^T) K   (V := K via KT)
//   phase 1: out = softmax(q2 K^T) V           (via VT)
// MFMA operands swapped (A=K/V-frags, B=Q/P-frags) so the C-layout holds
// contiguous k-dim per lane: P stores = b64 packed writes, P/Q reloads = b128.
// Fixed-max softmax (|score| <= ~3.3, exp2 safe). Block = 128 q-rows x 1 head,
// 4 waves x 32 rows. In-place safe (block reads only its own q cells first).
// ---------------------------------------------------------------------------
__global__ __launch_bounds__(256) void attn_fused(
  unsigned short* __restrict__ QO,
  const unsigned short* __restrict__ K,
  const unsigned short* __restrict__ KT,
  const unsigned short* __restrict__ VT)
{
  int qt = blockIdx.x;           // 0..31
  int h  = blockIdx.y;           // 0..15
  int b  = qt >> 4;
  int bh = b*H_ + h;
  int tid = threadIdx.x, w = tid>>6, l = tid&63;
  int lr = l&15, qd = l>>4;
  int r8 = tid>>3, c8 = (tid&7)*8;
  int chf = c8>>5, co = c8&31;

  __shared__ __align__(16) unsigned short sK[2][64*40];   // [d-half][key*40 + d%32]
  __shared__ __align__(16) unsigned short sV[2][64*40];   // [s-half][d*40 + s%32]
  __shared__ __align__(16) unsigned short sP[4][32*72];   // per-wave [q][s or d], stride 72

  const f32x4 fz = {0.f,0.f,0.f,0.f};

  // Q fragments (B-operand layout [q][d]) direct from global; q pre-scaled by CE_
  unsigned short* Qbase = QO + (size_t)(qt*128 + w*32)*D_ + h*64;
  short8 qf[2][2];
  #pragma unroll
  for (int gg=0; gg<2; gg++)
    #pragma unroll
    for (int hf=0; hf<2; hf++)
      qf[gg][hf] = *(const short8*)(Qbase + (size_t)(gg*16+lr)*D_ + hf*32 + qd*8);

  const unsigned short* Khead = K + (size_t)(b*S_)*D_ + h*64;
  unsigned short* Pw = &sP[w][0];

  f32x4 oacc[2][4];   // [gg][dt], holds O^T: lane (d=dt*16+qd*4+r, q=gg*16+lr)
  float lac[2];

  #pragma unroll 1
  for (int phase=0; phase<2; phase++){
    const unsigned short* Vhead = (phase ? VT : KT) + (size_t)bh*HD_*S_;
    lac[0]=0.f; lac[1]=0.f;
    #pragma unroll
    for (int gg=0;gg<2;gg++)
      #pragma unroll
      for (int t=0;t<4;t++) oacc[gg][t]=fz;

    for (int kt=0; kt<S_; kt+=64){
      __syncthreads();
      *(uint4*)(&sK[chf][(r8   )*40 + co]) = *(const uint4*)(Khead + (size_t)(kt+r8   )*D_ + c8);
      *(uint4*)(&sK[chf][(r8+32)*40 + co]) = *(const uint4*)(Khead + (size_t)(kt+r8+32)*D_ + c8);
      *(uint4*)(&sV[chf][(r8   )*40 + co]) = *(const uint4*)(Vhead + (size_t)(r8   )*S_ + kt + c8);
      *(uint4*)(&sV[chf][(r8+32)*40 + co]) = *(const uint4*)(Vhead + (size_t)(r8+32)*S_ + kt + c8);
      __syncthreads();

      // S^T strip: 64 keys x 32 q-rows per wave. A=K-frag, B=Q-frag.
      f32x4 sc[2][4];
      #pragma unroll
      for (int st=0; st<4; st++){
        short8 kA0 = *(const short8*)(&sK[0][(st*16+lr)*40 + qd*8]);
        short8 kA1 = *(const short8*)(&sK[1][(st*16+lr)*40 + qd*8]);
        #pragma unroll
        for (int gg=0; gg<2; gg++){
          f32x4 z = fz;
          z = __builtin_amdgcn_mfma_f32_16x16x32_bf16(kA0, qf[gg][0], z, 0,0,0);
          z = __builtin_amdgcn_mfma_f32_16x16x32_bf16(kA1, qf[gg][1], z, 0,0,0);
          sc[gg][st] = z;
        }
      }
      // exp2 (CE prefolded into q), row-sum in-lane, packed b64 store to sP[q][s]
      #pragma unroll
      for (int gg=0; gg<2; gg++)
        #pragma unroll
        for (int st=0; st<4; st++){
          float p0=exp2f(sc[gg][st][0]), p1=exp2f(sc[gg][st][1]);
          float p2=exp2f(sc[gg][st][2]), p3=exp2f(sc[gg][st][3]);
          lac[gg] += (p0+p1)+(p2+p3);
          uint2 pk; pk.x = pk2bf(p0,p1); pk.y = pk2bf(p2,p3);
          *(uint2*)(Pw + (gg*16+lr)*72 + st*16 + qd*4) = pk;
        }
      // P fragments (B-operand layout [q][s]) — wave-private, lgkm-ordered
      short8 pf[2][2];
      #pragma unroll
      for (int gg=0; gg<2; gg++){
        pf[gg][0] = *(const short8*)(Pw + (gg*16+lr)*72      + qd*8);
        pf[gg][1] = *(const short8*)(Pw + (gg*16+lr)*72 + 32 + qd*8);
      }
      // O^T += V^T-frag * P-frag
      #pragma unroll
      for (int dt=0; dt<4; dt++){
        short8 vA0 = *(const short8*)(&sV[0][(dt*16+lr)*40 + qd*8]);
        short8 vA1 = *(const short8*)(&sV[1][(dt*16+lr)*40 + qd*8]);
        #pragma unroll
        for (int gg=0; gg<2; gg++){
          oacc[gg][dt] = __builtin_amdgcn_mfma_f32_16x16x32_bf16(vA0, pf[gg][0], oacc[gg][dt], 0,0,0);
          oacc[gg][dt] = __builtin_amdgcn_mfma_f32_16x16x32_bf16(vA1, pf[gg][1], oacc[gg][dt], 0,0,0);
        }
      }
    } // kt

    // complete row-sums: reduce across the 4 quads (lanes l, l+16, l+32, l+48)
    #pragma unroll
    for (int gg=0;gg<2;gg++){
      lac[gg] += __shfl_xor(lac[gg], 16, 64);
      lac[gg] += __shfl_xor(lac[gg], 32, 64);
    }

    if (phase==0){
      // q2 = O^T/l, rescaled by CE_, back to Q-frags via sP[q][d]
      #pragma unroll
      for (int gg=0;gg<2;gg++){
        float iv = CE_ / lac[gg];
        #pragma unroll
        for (int dt=0;dt<4;dt++){
          uint2 pk;
          pk.x = pk2bf(oacc[gg][dt][0]*iv, oacc[gg][dt][1]*iv);
          pk.y = pk2bf(oacc[gg][dt][2]*iv, oacc[gg][dt][3]*iv);
          *(uint2*)(Pw + (gg*16+lr)*72 + dt*16 + qd*4) = pk;
        }
      }
      #pragma unroll
      for (int gg=0;gg<2;gg++){
        qf[gg][0] = *(const short8*)(Pw + (gg*16+lr)*72      + qd*8);
        qf[gg][1] = *(const short8*)(Pw + (gg*16+lr)*72 + 32 + qd*8);
      }
    } else {
      // final store: lane holds O^T(d = h*64+dt*16+qd*4+r, q = qt*128+w*32+gg*16+lr)
      #pragma unroll
      for (int gg=0;gg<2;gg++){
        float iv = 1.0f / lac[gg];
        unsigned short* Ob = QO + (size_t)(qt*128 + w*32 + gg*16 + lr)*D_ + h*64;
        #pragma unroll
        for (int dt=0;dt<4;dt++){
          uint2 pk;
          pk.x = pk2bf(oacc[gg][dt][0]*iv, oacc[gg][dt][1]*iv);
          pk.y = pk2bf(oacc[gg][dt][2]*iv, oacc[gg][dt][3]*iv);
          *(uint2*)(Ob + dt*16 + qd*4) = pk;
        }
      }
    }
  } // phase
}

// ---------------------------------------------------------------------------
extern "C" void kernel_launch(void* const* d_in, const int* in_sizes, int n_in,
                              void* d_out, int out_size, void* d_ws, size_t ws_size,
                              hipStream_t stream){
  const float* data = (const float*)d_in[0];
  const float* g_k  = (const float*)d_in[1];
  const float* b_k  = (const float*)d_in[2];
  const float* g_q  = (const float*)d_in[3];
  const float* b_q  = (const float*)d_in[4];
  const float* g_v  = (const float*)d_in[5];
  const float* b_v  = (const float*)d_in[6];
  const float* Wq   = (const float*)d_in[7];
  const float* bq   = (const float*)d_in[8];
  const float* Wk   = (const float*)d_in[9];
  const float* bk   = (const float*)d_in[10];
  const float* Wv   = (const float*)d_in[11];
  const float* bv   = (const float*)d_in[12];
  const float* Wo   = (const float*)d_in[13];
  const float* bo   = (const float*)d_in[14];
  float* out = (float*)d_out;

  char* ws = (char*)d_ws;
  const size_t MB = (size_t)1<<20;
  unsigned short* q    = (unsigned short*)(ws);           // [0,8) MB
  unsigned short* kb   = (unsigned short*)(ws + 8*MB);    // [8,16) MB
  unsigned short* kT   = (unsigned short*)(ws + 16*MB);   // [16,24) MB
  float*          bfld = (float*)(ws + 24*MB);            // 3*1024 f32
  float*          mean = bfld + 3*D_;                     // 4096 f32
  float*          rstd = mean + M_;                       // 4096 f32
  unsigned short* vT   = (unsigned short*)d_out;          // first 8MB of d_out

  dim3 gb(256);
  stats_kernel<<<dim3(M_/4), gb, 0, stream>>>(data, mean, rstd);
  biasfold_kernel<<<dim3(16,3), gb, 0, stream>>>(Wq,Wk,Wv, b_q,b_k,b_v, bq,bk,bv, bfld);
  gemm_qkv<<<dim3(32,8,3), gb, 0, stream>>>(data, Wq,Wk,Wv, g_q,g_k,g_v,
                                            bfld, mean, rstd, q, kb, kT, vT);
  attn_fused<<<dim3(32, H_), gb, 0, stream>>>(q, kb, kT, vT);
  gemm_out<<<dim3(32,8), gb, 0, stream>>>(q, Wo, bo, out);
}

// Round 7
// 352.604 us; speedup vs baseline: 1.8908x; 1.0994x over previous
//
#include <hip/hip_runtime.h>
#include <hip/hip_bf16.h>

// Problem constants
#define B_  2
#define S_  2048
#define D_  1024
#define H_  16
#define HD_ 64
#define M_  4096   // B_*S_

// Inputs/outputs f32; internal compute bf16 MFMA with f32 accumulation.
//
// ws (24 MB + 45 KB, proven):
//   [0,8)MB  q bf16 (CE-prescaled; attn in-place)   [8,16)MB kb bf16
//   [16,24)MB kT bf16 [bh][d][s]                    +24MB: biasf/mean/rstd
// d_out (16 MB) as scratch:
//   [0,8)MB  vT bf16 [bh][d][s]
//   [8,16)MB WT bf16: 4 x [1024][1024] (WTq CE*g-scaled, WTk/v g-scaled, WTo plain)
// gemm_out writes C f32 into ws[8,24) (kb/kT dead), then 16MB d2d -> d_out.
// Alias check: wtrans W(d_out[8,16)) ; gemm_qkv R WT, W q,kb,kT,vT(d_out[0,8)) ;
// attn R q,kb,kT,vT W q ; gemm_out R q,WTo W ws[8,24) ; memcpy -> d_out. All ordered.

typedef __attribute__((ext_vector_type(8))) short short8;
typedef __attribute__((ext_vector_type(4))) float f32x4;

#define CE_ 0.1803368801111204f   // 0.125 * log2(e)

static __device__ __forceinline__ unsigned short f2bfc(float f){
  union{float f; unsigned u;} c; c.f = f;
  return (unsigned short)((c.u + 0x8000u) >> 16);       // round-half-up
}
// pack two f32 -> packed bf16x2 (round-half-up)
static __device__ __forceinline__ unsigned pk2bf(float a, float b){
  union{float f; unsigned u;} ca, cb; ca.f=a; cb.f=b;
  return __builtin_amdgcn_perm(cb.u + 0x8000u, ca.u + 0x8000u, 0x07060302u);
}
// truncating pack (P matrix only; bias analysis: ~6e-5 abs effect on output)
static __device__ __forceinline__ unsigned pk2bft(float a, float b){
  union{float f; unsigned u;} ca, cb; ca.f=a; cb.f=b;
  return __builtin_amdgcn_perm(cb.u, ca.u, 0x07060302u);
}

// ---------------------------------------------------------------------------
// Per-row LN stats of data (f32): mean[row], rstd[row]. One wave per row.
// ---------------------------------------------------------------------------
__global__ __launch_bounds__(256) void stats_kernel(const float* __restrict__ x,
                                                    float* __restrict__ mean,
                                                    float* __restrict__ rstd){
  int row = blockIdx.x*4 + (threadIdx.x>>6);
  int l = threadIdx.x & 63;
  const float4* xr = (const float4*)(x + (size_t)row*D_);
  float s = 0.f, ss = 0.f;
  #pragma unroll
  for (int i=0;i<4;i++){
    float4 v = xr[l + 64*i];
    s  += v.x+v.y+v.z+v.w;
    ss += v.x*v.x+v.y*v.y+v.z*v.z+v.w*v.w;
  }
  #pragma unroll
  for (int m=1;m<64;m<<=1){ s += __shfl_xor(s, m, 64); ss += __shfl_xor(ss, m, 64); }
  if (l==0){
    float me = s*(1.0f/D_);
    float var = ss*(1.0f/D_) - me*me;
    mean[row] = me;
    rstd[row] = rsqrtf(var + 1e-5f);
  }
}

// ---------------------------------------------------------------------------
// Folded bias: biasf[z][n] = (bp_z[n] + sum_k bln_z[k]*W_z[k][n]) * (z==0?CE:1)
// ---------------------------------------------------------------------------
__global__ __launch_bounds__(256) void biasfold_kernel(
  const float* __restrict__ Wq, const float* __restrict__ Wk, const float* __restrict__ Wv,
  const float* __restrict__ blq, const float* __restrict__ blk, const float* __restrict__ blv,
  const float* __restrict__ bpq, const float* __restrict__ bpk, const float* __restrict__ bpv,
  float* __restrict__ bf){
  int z = blockIdx.y;
  const float* W  = (z==0)?Wq:(z==1)?Wk:Wv;
  const float* bl = (z==0)?blq:(z==1)?blk:blv;
  const float* bp = (z==0)?bpq:(z==1)?bpk:bpv;
  int nl = threadIdx.x & 63, kg = threadIdx.x >> 6;
  int n = blockIdx.x*64 + nl;
  float acc = 0.f;
  for (int k = kg*256; k < (kg+1)*256; k++)
    acc += bl[k] * W[(size_t)k*D_ + n];
  __shared__ float red[4][64];
  red[kg][nl] = acc;
  __syncthreads();
  if (threadIdx.x < 64){
    int nn = blockIdx.x*64 + threadIdx.x;
    float v = red[0][threadIdx.x]+red[1][threadIdx.x]+red[2][threadIdx.x]+red[3][threadIdx.x]
              + bp[nn];
    bf[z*D_ + nn] = (z==0) ? v*CE_ : v;
  }
}

// ---------------------------------------------------------------------------
// Weight transpose + cast: WT[z][n][k] = scale_z[k] * W_z[k][n]  (bf16 out)
// scale: z0 = CE*g_q[k], z1 = g_k[k], z2 = g_v[k], z3 = 1.
// grid (16,16,4), 64x64 tiles.
// ---------------------------------------------------------------------------
__global__ __launch_bounds__(256) void wtrans_kernel(
  const float* __restrict__ Wq, const float* __restrict__ Wk,
  const float* __restrict__ Wv, const float* __restrict__ Wo,
  const float* __restrict__ gq, const float* __restrict__ gk,
  const float* __restrict__ gv,
  unsigned short* __restrict__ WT){
  int z = blockIdx.z;
  const float* W = (z==0)?Wq:(z==1)?Wk:(z==2)?Wv:Wo;
  const float* g = (z==0)?gq:(z==1)?gk:(z==2)?gv:(const float*)0;
  unsigned short* out = WT + ((size_t)z<<20);
  int k0 = blockIdx.x*64, n0 = blockIdx.y*64;
  __shared__ unsigned short tile[64][72];
  int t = threadIdx.x;
  { // read W rows (coalesced along n), scale+cast, stash in LDS
    int kr = t>>2, c16 = (t&3)*16;
    float gs = g ? g[k0+kr]*((z==0)?CE_:1.0f) : 1.0f;
    const float* src = W + (size_t)(k0+kr)*D_ + n0 + c16;
    float4 w0 = *(const float4*)(src);
    float4 w1 = *(const float4*)(src+4);
    float4 w2 = *(const float4*)(src+8);
    float4 w3 = *(const float4*)(src+12);
    unsigned* tp = (unsigned*)&tile[kr][c16];
    tp[0]=pk2bf(w0.x*gs,w0.y*gs); tp[1]=pk2bf(w0.z*gs,w0.w*gs);
    tp[2]=pk2bf(w1.x*gs,w1.y*gs); tp[3]=pk2bf(w1.z*gs,w1.w*gs);
    tp[4]=pk2bf(w2.x*gs,w2.y*gs); tp[5]=pk2bf(w2.z*gs,w2.w*gs);
    tp[6]=pk2bf(w3.x*gs,w3.y*gs); tp[7]=pk2bf(w3.z*gs,w3.w*gs);
  }
  __syncthreads();
  { // write WT rows (coalesced along k)
    int nr = t>>2, kc = (t&3)*16;
    union { uint4 v[2]; unsigned short u[16]; } st;
    #pragma unroll
    for (int i=0;i<16;i++) st.u[i] = tile[kc+i][nr];
    unsigned short* dst = out + (size_t)(n0+nr)*D_ + k0 + kc;
    *(uint4*)(dst)     = st.v[0];
    *(uint4*)(dst + 8) = st.v[1];
  }
}

// ---------------------------------------------------------------------------
// Fused QKV GEMM, grid (32,8,3): z in {q,k,v}. 128x128 tile, 4 waves.
// A = f32 data with on-the-fly LN; B = WT[z] bf16 [n][k] (pre-scaled).
// Outputs: z0 -> q row-major; z1 -> kb + kT [bh][d][s]; z2 -> vT.
// ---------------------------------------------------------------------------
__global__ __launch_bounds__(256) void gemm_qkv(
  const float* __restrict__ data,
  const unsigned short* __restrict__ WT,
  const float* __restrict__ biasf,
  const float* __restrict__ mean, const float* __restrict__ rstd,
  unsigned short* __restrict__ qv, unsigned short* __restrict__ kb,
  unsigned short* __restrict__ kT, unsigned short* __restrict__ vT)
{
  int z = blockIdx.z;
  const unsigned short* Bt = WT + ((size_t)z<<20);
  const float* bias = biasf + z*D_;
  unsigned short* oN = (z==0)?qv:(z==1)?kb:(unsigned short*)0;
  unsigned short* oT = (z==0)?(unsigned short*)0:(z==1)?kT:vT;

  __shared__ __align__(16) unsigned short As[128*40];
  __shared__ __align__(16) unsigned short Bs[128*40];
  int tid = threadIdx.x, w = tid>>6, l = tid&63;
  int m0 = blockIdx.x*128, n0 = blockIdx.y*128;
  int wr = (w>>1)*64, wc = (w&1)*64;
  int lr = l&15, qd = l>>4;
  int srow = tid>>2, scol = (tid&3)*8;

  float me0 = mean[m0+srow],    rs0 = rstd[m0+srow];
  float me1 = mean[m0+srow+64], rs1 = rstd[m0+srow+64];

  const f32x4 fz = {0.f,0.f,0.f,0.f};
  f32x4 acc[4][4];
  #pragma unroll
  for (int i=0;i<4;i++)
    #pragma unroll
    for (int j=0;j<4;j++) acc[i][j] = fz;

  for (int kk=0; kk<D_; kk+=32){
    __syncthreads();
    { // A tile with LN, packed converts
      const float* p0 = data + (size_t)(m0+srow   )*D_ + kk + scol;
      const float* p1 = data + (size_t)(m0+srow+64)*D_ + kk + scol;
      float4 a0 = *(const float4*)(p0), a0b = *(const float4*)(p0+4);
      float4 a1 = *(const float4*)(p1), a1b = *(const float4*)(p1+4);
      uint4 o0, o1;
      o0.x = pk2bf((a0.x -me0)*rs0, (a0.y -me0)*rs0);
      o0.y = pk2bf((a0.z -me0)*rs0, (a0.w -me0)*rs0);
      o0.z = pk2bf((a0b.x-me0)*rs0, (a0b.y-me0)*rs0);
      o0.w = pk2bf((a0b.z-me0)*rs0, (a0b.w-me0)*rs0);
      o1.x = pk2bf((a1.x -me1)*rs1, (a1.y -me1)*rs1);
      o1.y = pk2bf((a1.z -me1)*rs1, (a1.w -me1)*rs1);
      o1.z = pk2bf((a1b.x-me1)*rs1, (a1b.y-me1)*rs1);
      o1.w = pk2bf((a1b.z-me1)*rs1, (a1b.w-me1)*rs1);
      *(uint4*)(As + srow*40      + scol) = o0;
      *(uint4*)(As + (srow+64)*40 + scol) = o1;
    }
    // B tile: straight b128 copies from WT[n][k]
    *(uint4*)(Bs + srow*40      + scol) = *(const uint4*)(Bt + (size_t)(n0+srow   )*D_ + kk + scol);
    *(uint4*)(Bs + (srow+64)*40 + scol) = *(const uint4*)(Bt + (size_t)(n0+srow+64)*D_ + kk + scol);
    __syncthreads();
    short8 af[4], bfr[4];
    #pragma unroll
    for (int i=0;i<4;i++) af[i]  = *(const short8*)(As + (wr + i*16 + lr)*40 + qd*8);
    #pragma unroll
    for (int j=0;j<4;j++) bfr[j] = *(const short8*)(Bs + (wc + j*16 + lr)*40 + qd*8);
    #pragma unroll
    for (int i=0;i<4;i++)
      #pragma unroll
      for (int j=0;j<4;j++)
        acc[i][j] = __builtin_amdgcn_mfma_f32_16x16x32_bf16(af[i], bfr[j], acc[i][j], 0, 0, 0);
  }

  #pragma unroll
  for (int j=0;j<4;j++){
    int n = n0 + wc + j*16 + lr;
    float bias_n = bias[n];
    #pragma unroll
    for (int i=0;i<4;i++){
      int mb = m0 + wr + i*16 + qd*4;
      float v0 = acc[i][j][0] + bias_n;
      float v1 = acc[i][j][1] + bias_n;
      float v2 = acc[i][j][2] + bias_n;
      float v3 = acc[i][j][3] + bias_n;
      if (oN){
        oN[(size_t)(mb+0)*D_ + n] = f2bfc(v0);
        oN[(size_t)(mb+1)*D_ + n] = f2bfc(v1);
        oN[(size_t)(mb+2)*D_ + n] = f2bfc(v2);
        oN[(size_t)(mb+3)*D_ + n] = f2bfc(v3);
      }
      if (oT){
        int bb = mb >> 11, sI = mb & (S_-1);
        int hh = n >> 6,  dd = n & 63;
        uint2 pk; pk.x = pk2bf(v0, v1); pk.y = pk2bf(v2, v3);
        *(uint2*)(oT + (size_t)((bb*H_ + hh)*HD_ + dd)*S_ + sI) = pk;
      }
    }
  }
}

// ---------------------------------------------------------------------------
// Out-projection: C = A(bf16) @ WTo^T + bo, f32 out (to ws scratch).
// ---------------------------------------------------------------------------
__global__ __launch_bounds__(256) void gemm_out(
  const unsigned short* __restrict__ A,
  const unsigned short* __restrict__ Bt,   // WTo [n][k] bf16
  const float* __restrict__ bo,
  float* __restrict__ Cf)
{
  __shared__ __align__(16) unsigned short As[128*40];
  __shared__ __align__(16) unsigned short Bs[128*40];
  int tid = threadIdx.x, w = tid>>6, l = tid&63;
  int m0 = blockIdx.x*128, n0 = blockIdx.y*128;
  int wr = (w>>1)*64, wc = (w&1)*64;
  int lr = l&15, qd = l>>4;
  int srow = tid>>2, scol = (tid&3)*8;

  const f32x4 fz = {0.f,0.f,0.f,0.f};
  f32x4 acc[4][4];
  #pragma unroll
  for (int i=0;i<4;i++)
    #pragma unroll
    for (int j=0;j<4;j++) acc[i][j] = fz;

  for (int kk=0; kk<D_; kk+=32){
    __syncthreads();
    *(uint4*)(As + srow*40      + scol) = *(const uint4*)(A  + (size_t)(m0+srow   )*D_ + kk + scol);
    *(uint4*)(As + (srow+64)*40 + scol) = *(const uint4*)(A  + (size_t)(m0+srow+64)*D_ + kk + scol);
    *(uint4*)(Bs + srow*40      + scol) = *(const uint4*)(Bt + (size_t)(n0+srow   )*D_ + kk + scol);
    *(uint4*)(Bs + (srow+64)*40 + scol) = *(const uint4*)(Bt + (size_t)(n0+srow+64)*D_ + kk + scol);
    __syncthreads();
    short8 af[4], bfr[4];
    #pragma unroll
    for (int i=0;i<4;i++) af[i]  = *(const short8*)(As + (wr + i*16 + lr)*40 + qd*8);
    #pragma unroll
    for (int j=0;j<4;j++) bfr[j] = *(const short8*)(Bs + (wc + j*16 + lr)*40 + qd*8);
    #pragma unroll
    for (int i=0;i<4;i++)
      #pragma unroll
      for (int j=0;j<4;j++)
        acc[i][j] = __builtin_amdgcn_mfma_f32_16x16x32_bf16(af[i], bfr[j], acc[i][j], 0, 0, 0);
  }

  #pragma unroll
  for (int j=0;j<4;j++){
    int n = n0 + wc + j*16 + lr;
    float bias_n = bo[n];
    #pragma unroll
    for (int i=0;i<4;i++){
      int mb = m0 + wr + i*16 + qd*4;
      Cf[(size_t)(mb+0)*D_ + n] = acc[i][j][0] + bias_n;
      Cf[(size_t)(mb+1)*D_ + n] = acc[i][j][1] + bias_n;
      Cf[(size_t)(mb+2)*D_ + n] = acc[i][j][2] + bias_n;
      Cf[(size_t)(mb+3)*D_ + n] = acc[i][j][3] + bias_n;
    }
  }
}

// ---------------------------------------------------------------------------
// Fused double Hopfield attention, transposed compute (S^T/O^T), in-place on
// QO (bf16, CE-prescaled). 64 q-rows per block, 4 waves x 16 rows, grid (64,16)
// = 1024 blocks (~4/CU). Split-half stride-40 LDS everywhere.
//   phase 0: q2 = softmax(q K^T) K  (via KT) ; phase 1: out = softmax(q2 K^T) V
// ---------------------------------------------------------------------------
__global__ __launch_bounds__(256) void attn_fused(
  unsigned short* __restrict__ QO,
  const unsigned short* __restrict__ K,
  const unsigned short* __restrict__ KT,
  const unsigned short* __restrict__ VT)
{
  int qt = blockIdx.x;           // 0..63 (64-row tile)
  int h  = blockIdx.y;           // 0..15
  int b  = qt >> 5;
  int bh = b*H_ + h;
  int tid = threadIdx.x, w = tid>>6, l = tid&63;
  int lr = l&15, qd = l>>4;
  int r8 = tid>>3, c8 = (tid&7)*8;
  int chf = c8>>5, co = c8&31;

  __shared__ __align__(16) unsigned short sK[2][64*40];   // [d-half][key*40 + d%32]
  __shared__ __align__(16) unsigned short sV[2][64*40];   // [s-half][d*40 + s%32]
  __shared__ __align__(16) unsigned short sP[4][2][16*40];// per-wave [half][q*40 + off]

  const f32x4 fz = {0.f,0.f,0.f,0.f};

  // Q fragments (B-operand [q][d]) straight from global; CE prefolded.
  unsigned short* Qbase = QO + (size_t)(qt*64 + w*16) * D_ + h*64;
  short8 qf[2];
  #pragma unroll
  for (int hf=0; hf<2; hf++)
    qf[hf] = *(const short8*)(Qbase + (size_t)lr*D_ + hf*32 + qd*8);

  const unsigned short* Khead = K + (size_t)(b*S_)*D_ + h*64;

  f32x4 oacc[4];   // O^T: lane (d = dt*16+qd*4+r, q = lr)
  float lac;

  #pragma unroll 1
  for (int phase=0; phase<2; phase++){
    const unsigned short* Vhead = (phase ? VT : KT) + (size_t)bh*HD_*S_;
    lac = 0.f;
    #pragma unroll
    for (int t=0;t<4;t++) oacc[t]=fz;

    for (int kt=0; kt<S_; kt+=64){
      __syncthreads();
      *(uint4*)(&sK[chf][(r8   )*40 + co]) = *(const uint4*)(Khead + (size_t)(kt+r8   )*D_ + c8);
      *(uint4*)(&sK[chf][(r8+32)*40 + co]) = *(const uint4*)(Khead + (size_t)(kt+r8+32)*D_ + c8);
      *(uint4*)(&sV[chf][(r8   )*40 + co]) = *(const uint4*)(Vhead + (size_t)(r8   )*S_ + kt + c8);
      *(uint4*)(&sV[chf][(r8+32)*40 + co]) = *(const uint4*)(Vhead + (size_t)(r8+32)*S_ + kt + c8);
      __syncthreads();

      // S^T strip: 64 keys x 16 q. A=K-frag, B=Q-frag.
      f32x4 sc[4];
      #pragma unroll
      for (int st=0; st<4; st++){
        short8 kA0 = *(const short8*)(&sK[0][(st*16+lr)*40 + qd*8]);
        short8 kA1 = *(const short8*)(&sK[1][(st*16+lr)*40 + qd*8]);
        f32x4 z = fz;
        z = __builtin_amdgcn_mfma_f32_16x16x32_bf16(kA0, qf[0], z, 0,0,0);
        z = __builtin_amdgcn_mfma_f32_16x16x32_bf16(kA1, qf[1], z, 0,0,0);
        sc[st] = z;
      }
      // exp2 (CE prefolded) + in-lane row-sum + packed b64 stores (truncating)
      #pragma unroll
      for (int st=0; st<4; st++){
        float p0=exp2f(sc[st][0]), p1=exp2f(sc[st][1]);
        float p2=exp2f(sc[st][2]), p3=exp2f(sc[st][3]);
        lac += (p0+p1)+(p2+p3);
        uint2 pk; pk.x = pk2bft(p0,p1); pk.y = pk2bft(p2,p3);
        *(uint2*)(&sP[w][st>>1][lr*40 + (st&1)*16 + qd*4]) = pk;
      }
      short8 pf0 = *(const short8*)(&sP[w][0][lr*40 + qd*8]);
      short8 pf1 = *(const short8*)(&sP[w][1][lr*40 + qd*8]);
      // O^T += V^T-frag * P-frag
      #pragma unroll
      for (int dt=0; dt<4; dt++){
        short8 vA0 = *(const short8*)(&sV[0][(dt*16+lr)*40 + qd*8]);
        short8 vA1 = *(const short8*)(&sV[1][(dt*16+lr)*40 + qd*8]);
        oacc[dt] = __builtin_amdgcn_mfma_f32_16x16x32_bf16(vA0, pf0, oacc[dt], 0,0,0);
        oacc[dt] = __builtin_amdgcn_mfma_f32_16x16x32_bf16(vA1, pf1, oacc[dt], 0,0,0);
      }
    } // kt

    // complete row-sum over the 4 quads
    lac += __shfl_xor(lac, 16, 64);
    lac += __shfl_xor(lac, 32, 64);

    if (phase==0){
      float iv = CE_ / lac;
      #pragma unroll
      for (int dt=0;dt<4;dt++){
        uint2 pk;
        pk.x = pk2bf(oacc[dt][0]*iv, oacc[dt][1]*iv);
        pk.y = pk2bf(oacc[dt][2]*iv, oacc[dt][3]*iv);
        *(uint2*)(&sP[w][dt>>1][lr*40 + (dt&1)*16 + qd*4]) = pk;
      }
      qf[0] = *(const short8*)(&sP[w][0][lr*40 + qd*8]);
      qf[1] = *(const short8*)(&sP[w][1][lr*40 + qd*8]);
    } else {
      float iv = 1.0f / lac;
      unsigned short* Ob = QO + (size_t)(qt*64 + w*16 + lr)*D_ + h*64;
      #pragma unroll
      for (int dt=0;dt<4;dt++){
        uint2 pk;
        pk.x = pk2bf(oacc[dt][0]*iv, oacc[dt][1]*iv);
        pk.y = pk2bf(oacc[dt][2]*iv, oacc[dt][3]*iv);
        *(uint2*)(Ob + dt*16 + qd*4) = pk;
      }
    }
  } // phase
}

// ---------------------------------------------------------------------------
extern "C" void kernel_launch(void* const* d_in, const int* in_sizes, int n_in,
                              void* d_out, int out_size, void* d_ws, size_t ws_size,
                              hipStream_t stream){
  const float* data = (const float*)d_in[0];
  const float* g_k  = (const float*)d_in[1];
  const float* b_k  = (const float*)d_in[2];
  const float* g_q  = (const float*)d_in[3];
  const float* b_q  = (const float*)d_in[4];
  const float* g_v  = (const float*)d_in[5];
  const float* b_v  = (const float*)d_in[6];
  const float* Wq   = (const float*)d_in[7];
  const float* bq   = (const float*)d_in[8];
  const float* Wk   = (const float*)d_in[9];
  const float* bk   = (const float*)d_in[10];
  const float* Wv   = (const float*)d_in[11];
  const float* bv   = (const float*)d_in[12];
  const float* Wo   = (const float*)d_in[13];
  const float* bo   = (const float*)d_in[14];

  char* ws = (char*)d_ws;
  const size_t MB = (size_t)1<<20;
  unsigned short* q    = (unsigned short*)(ws);           // [0,8) MB
  unsigned short* kb   = (unsigned short*)(ws + 8*MB);    // [8,16) MB
  unsigned short* kT   = (unsigned short*)(ws + 16*MB);   // [16,24) MB
  float*          Cws  = (float*)(ws + 8*MB);             // ogemm C (kb/kT dead)
  float*          bfld = (float*)(ws + 24*MB);            // 3*1024 f32
  float*          mean = bfld + 3*D_;                     // 4096 f32
  float*          rstd = mean + M_;                       // 4096 f32
  unsigned short* vT   = (unsigned short*)d_out;          // d_out[0,8) MB
  unsigned short* WT   = (unsigned short*)((char*)d_out + 8*MB);  // d_out[8,16) MB
  unsigned short* WTo  = WT + ((size_t)3<<20);

  dim3 gb(256);
  stats_kernel<<<dim3(M_/4), gb, 0, stream>>>(data, mean, rstd);
  biasfold_kernel<<<dim3(16,3), gb, 0, stream>>>(Wq,Wk,Wv, b_q,b_k,b_v, bq,bk,bv, bfld);
  wtrans_kernel<<<dim3(16,16,4), gb, 0, stream>>>(Wq,Wk,Wv,Wo, g_q,g_k,g_v, WT);
  gemm_qkv<<<dim3(32,8,3), gb, 0, stream>>>(data, WT, bfld, mean, rstd, q, kb, kT, vT);
  attn_fused<<<dim3(64, H_), gb, 0, stream>>>(q, kb, kT, vT);
  gemm_out<<<dim3(32,8), gb, 0, stream>>>(q, WTo, bo, Cws);
  hipMemcpyAsync(d_out, Cws, (size_t)M_*D_*sizeof(float),
                 hipMemcpyDeviceToDevice, stream);
}

// Round 8
// 324.028 us; speedup vs baseline: 2.0576x; 1.0882x over previous
//
#include <hip/hip_runtime.h>
#include <hip/hip_bf16.h>

// Problem constants
#define B_  2
#define S_  2048
#define D_  1024
#define H_  16
#define HD_ 64
#define M_  4096   // B_*S_

// Inputs/outputs f32; internal compute bf16 MFMA with f32 accumulation.
//
// ws (24 MB + 45 KB, proven ceiling):
//   [0,8)MB  q bf16 (CE-prescaled; attn in-place)
//   [8,16)MB kb bf16
//   [16,24)MB WT bf16: 4 x [1024][1024] ([q CE*g | k g | v g | o plain])
//   +24MB: biasf f32[3][1024], mean f32[4096], rstd f32[4096]
// d_out (16 MB f32) as scratch until the final GEMM:
//   [0,8)MB  vT bf16 [bh][d][s]     [8,16)MB kT bf16 [bh][d][s]
// gemm_out reads q + WT[o] (both in ws) and writes d_out directly (vT/kT dead).
// LDS row stride everywhere: 56 shorts (112B) -> b128 frag reads are
// conflict-free (bank 28*lr+4*qd, only the free 2-way lr/lr+8 aliasing).

typedef __attribute__((ext_vector_type(8))) short short8;
typedef __attribute__((ext_vector_type(4))) float f32x4;

#define CE_ 0.1803368801111204f   // 0.125 * log2(e)
#define SD_ 56                    // LDS row stride in shorts

static __device__ __forceinline__ unsigned short f2bfc(float f){
  union{float f; unsigned u;} c; c.f = f;
  return (unsigned short)((c.u + 0x8000u) >> 16);       // round-half-up
}
static __device__ __forceinline__ unsigned pk2bf(float a, float b){
  union{float f; unsigned u;} ca, cb; ca.f=a; cb.f=b;
  return __builtin_amdgcn_perm(cb.u + 0x8000u, ca.u + 0x8000u, 0x07060302u);
}
static __device__ __forceinline__ unsigned pk2bft(float a, float b){
  union{float f; unsigned u;} ca, cb; ca.f=a; cb.f=b;
  return __builtin_amdgcn_perm(cb.u, ca.u, 0x07060302u);
}

// ---------------------------------------------------------------------------
// Per-row LN stats of data (f32): mean[row], rstd[row]. One wave per row.
// ---------------------------------------------------------------------------
__global__ __launch_bounds__(256) void stats_kernel(const float* __restrict__ x,
                                                    float* __restrict__ mean,
                                                    float* __restrict__ rstd){
  int row = blockIdx.x*4 + (threadIdx.x>>6);
  int l = threadIdx.x & 63;
  const float4* xr = (const float4*)(x + (size_t)row*D_);
  float s = 0.f, ss = 0.f;
  #pragma unroll
  for (int i=0;i<4;i++){
    float4 v = xr[l + 64*i];
    s  += v.x+v.y+v.z+v.w;
    ss += v.x*v.x+v.y*v.y+v.z*v.z+v.w*v.w;
  }
  #pragma unroll
  for (int m=1;m<64;m<<=1){ s += __shfl_xor(s, m, 64); ss += __shfl_xor(ss, m, 64); }
  if (l==0){
    float me = s*(1.0f/D_);
    float var = ss*(1.0f/D_) - me*me;
    mean[row] = me;
    rstd[row] = rsqrtf(var + 1e-5f);
  }
}

// ---------------------------------------------------------------------------
// Folded bias: biasf[z][n] = (bp_z[n] + sum_k bln_z[k]*W_z[k][n]) * (z==0?CE:1)
// ---------------------------------------------------------------------------
__global__ __launch_bounds__(256) void biasfold_kernel(
  const float* __restrict__ Wq, const float* __restrict__ Wk, const float* __restrict__ Wv,
  const float* __restrict__ blq, const float* __restrict__ blk, const float* __restrict__ blv,
  const float* __restrict__ bpq, const float* __restrict__ bpk, const float* __restrict__ bpv,
  float* __restrict__ bf){
  int z = blockIdx.y;
  const float* W  = (z==0)?Wq:(z==1)?Wk:Wv;
  const float* bl = (z==0)?blq:(z==1)?blk:blv;
  const float* bp = (z==0)?bpq:(z==1)?bpk:bpv;
  int nl = threadIdx.x & 63, kg = threadIdx.x >> 6;
  int n = blockIdx.x*64 + nl;
  float acc = 0.f;
  for (int k = kg*256; k < (kg+1)*256; k++)
    acc += bl[k] * W[(size_t)k*D_ + n];
  __shared__ float red[4][64];
  red[kg][nl] = acc;
  __syncthreads();
  if (threadIdx.x < 64){
    int nn = blockIdx.x*64 + threadIdx.x;
    float v = red[0][threadIdx.x]+red[1][threadIdx.x]+red[2][threadIdx.x]+red[3][threadIdx.x]
              + bp[nn];
    bf[z*D_ + nn] = (z==0) ? v*CE_ : v;
  }
}

// ---------------------------------------------------------------------------
// Weight transpose + cast: WT[z][n][k] = scale_z[k] * W_z[k][n]  (bf16 out)
// scale: z0 = CE*g_q[k], z1 = g_k[k], z2 = g_v[k], z3 = 1.  grid (16,16,4).
// ---------------------------------------------------------------------------
__global__ __launch_bounds__(256) void wtrans_kernel(
  const float* __restrict__ Wq, const float* __restrict__ Wk,
  const float* __restrict__ Wv, const float* __restrict__ Wo,
  const float* __restrict__ gq, const float* __restrict__ gk,
  const float* __restrict__ gv,
  unsigned short* __restrict__ WT){
  int z = blockIdx.z;
  const float* W = (z==0)?Wq:(z==1)?Wk:(z==2)?Wv:Wo;
  const float* g = (z==0)?gq:(z==1)?gk:(z==2)?gv:(const float*)0;
  unsigned short* out = WT + ((size_t)z<<20);
  int k0 = blockIdx.x*64, n0 = blockIdx.y*64;
  __shared__ unsigned short tile[64][72];
  int t = threadIdx.x;
  {
    int kr = t>>2, c16 = (t&3)*16;
    float gs = g ? g[k0+kr]*((z==0)?CE_:1.0f) : 1.0f;
    const float* src = W + (size_t)(k0+kr)*D_ + n0 + c16;
    float4 w0 = *(const float4*)(src);
    float4 w1 = *(const float4*)(src+4);
    float4 w2 = *(const float4*)(src+8);
    float4 w3 = *(const float4*)(src+12);
    unsigned* tp = (unsigned*)&tile[kr][c16];
    tp[0]=pk2bf(w0.x*gs,w0.y*gs); tp[1]=pk2bf(w0.z*gs,w0.w*gs);
    tp[2]=pk2bf(w1.x*gs,w1.y*gs); tp[3]=pk2bf(w1.z*gs,w1.w*gs);
    tp[4]=pk2bf(w2.x*gs,w2.y*gs); tp[5]=pk2bf(w2.z*gs,w2.w*gs);
    tp[6]=pk2bf(w3.x*gs,w3.y*gs); tp[7]=pk2bf(w3.z*gs,w3.w*gs);
  }
  __syncthreads();
  {
    int nr = t>>2, kc = (t&3)*16;
    union { uint4 v[2]; unsigned short u[16]; } st;
    #pragma unroll
    for (int i=0;i<16;i++) st.u[i] = tile[kc+i][nr];
    unsigned short* dst = out + (size_t)(n0+nr)*D_ + k0 + kc;
    *(uint4*)(dst)     = st.v[0];
    *(uint4*)(dst + 8) = st.v[1];
  }
}

// ---------------------------------------------------------------------------
// Fused QKV GEMM, grid (32,8,3). 128x128 tile, 4 waves, stride-56 LDS.
// A = f32 data + on-the-fly LN; B = WT[z] bf16 [n][k].
// z0 -> q row-major; z1 -> kb + kT [bh][d][s] (d_out); z2 -> vT (d_out).
// ---------------------------------------------------------------------------
__global__ __launch_bounds__(256) void gemm_qkv(
  const float* __restrict__ data,
  const unsigned short* __restrict__ WT,
  const float* __restrict__ biasf,
  const float* __restrict__ mean, const float* __restrict__ rstd,
  unsigned short* __restrict__ qv, unsigned short* __restrict__ kb,
  unsigned short* __restrict__ kT, unsigned short* __restrict__ vT)
{
  int z = blockIdx.z;
  const unsigned short* Bt = WT + ((size_t)z<<20);
  const float* bias = biasf + z*D_;
  unsigned short* oN = (z==0)?qv:(z==1)?kb:(unsigned short*)0;
  unsigned short* oT = (z==0)?(unsigned short*)0:(z==1)?kT:vT;

  __shared__ __align__(16) unsigned short As[128*SD_];
  __shared__ __align__(16) unsigned short Bs[128*SD_];
  int tid = threadIdx.x, w = tid>>6, l = tid&63;
  int m0 = blockIdx.x*128, n0 = blockIdx.y*128;
  int wr = (w>>1)*64, wc = (w&1)*64;
  int lr = l&15, qd = l>>4;
  int srow = tid>>2, scol = (tid&3)*8;

  float me0 = mean[m0+srow],    rs0 = rstd[m0+srow];
  float me1 = mean[m0+srow+64], rs1 = rstd[m0+srow+64];

  const f32x4 fz = {0.f,0.f,0.f,0.f};
  f32x4 acc[4][4];
  #pragma unroll
  for (int i=0;i<4;i++)
    #pragma unroll
    for (int j=0;j<4;j++) acc[i][j] = fz;

  for (int kk=0; kk<D_; kk+=32){
    __syncthreads();
    {
      const float* p0 = data + (size_t)(m0+srow   )*D_ + kk + scol;
      const float* p1 = data + (size_t)(m0+srow+64)*D_ + kk + scol;
      float4 a0 = *(const float4*)(p0), a0b = *(const float4*)(p0+4);
      float4 a1 = *(const float4*)(p1), a1b = *(const float4*)(p1+4);
      uint4 o0, o1;
      o0.x = pk2bf((a0.x -me0)*rs0, (a0.y -me0)*rs0);
      o0.y = pk2bf((a0.z -me0)*rs0, (a0.w -me0)*rs0);
      o0.z = pk2bf((a0b.x-me0)*rs0, (a0b.y-me0)*rs0);
      o0.w = pk2bf((a0b.z-me0)*rs0, (a0b.w-me0)*rs0);
      o1.x = pk2bf((a1.x -me1)*rs1, (a1.y -me1)*rs1);
      o1.y = pk2bf((a1.z -me1)*rs1, (a1.w -me1)*rs1);
      o1.z = pk2bf((a1b.x-me1)*rs1, (a1b.y-me1)*rs1);
      o1.w = pk2bf((a1b.z-me1)*rs1, (a1b.w-me1)*rs1);
      *(uint4*)(As + srow*SD_      + scol) = o0;
      *(uint4*)(As + (srow+64)*SD_ + scol) = o1;
    }
    *(uint4*)(Bs + srow*SD_      + scol) = *(const uint4*)(Bt + (size_t)(n0+srow   )*D_ + kk + scol);
    *(uint4*)(Bs + (srow+64)*SD_ + scol) = *(const uint4*)(Bt + (size_t)(n0+srow+64)*D_ + kk + scol);
    __syncthreads();
    short8 af[4], bfr[4];
    #pragma unroll
    for (int i=0;i<4;i++) af[i]  = *(const short8*)(As + (wr + i*16 + lr)*SD_ + qd*8);
    #pragma unroll
    for (int j=0;j<4;j++) bfr[j] = *(const short8*)(Bs + (wc + j*16 + lr)*SD_ + qd*8);
    #pragma unroll
    for (int i=0;i<4;i++)
      #pragma unroll
      for (int j=0;j<4;j++)
        acc[i][j] = __builtin_amdgcn_mfma_f32_16x16x32_bf16(af[i], bfr[j], acc[i][j], 0, 0, 0);
  }

  #pragma unroll
  for (int j=0;j<4;j++){
    int n = n0 + wc + j*16 + lr;
    float bias_n = bias[n];
    #pragma unroll
    for (int i=0;i<4;i++){
      int mb = m0 + wr + i*16 + qd*4;
      float v0 = acc[i][j][0] + bias_n;
      float v1 = acc[i][j][1] + bias_n;
      float v2 = acc[i][j][2] + bias_n;
      float v3 = acc[i][j][3] + bias_n;
      if (oN){
        oN[(size_t)(mb+0)*D_ + n] = f2bfc(v0);
        oN[(size_t)(mb+1)*D_ + n] = f2bfc(v1);
        oN[(size_t)(mb+2)*D_ + n] = f2bfc(v2);
        oN[(size_t)(mb+3)*D_ + n] = f2bfc(v3);
      }
      if (oT){
        int bb = mb >> 11, sI = mb & (S_-1);
        int hh = n >> 6,  dd = n & 63;
        uint2 pk; pk.x = pk2bf(v0, v1); pk.y = pk2bf(v2, v3);
        *(uint2*)(oT + (size_t)((bb*H_ + hh)*HD_ + dd)*S_ + sI) = pk;
      }
    }
  }
}

// ---------------------------------------------------------------------------
// Out-projection: C = A(bf16) @ WTo^T + bo, f32 straight to d_out.
// ---------------------------------------------------------------------------
__global__ __launch_bounds__(256) void gemm_out(
  const unsigned short* __restrict__ A,
  const unsigned short* __restrict__ Bt,   // WTo [n][k] bf16 (in ws)
  const float* __restrict__ bo,
  float* __restrict__ Cf)
{
  __shared__ __align__(16) unsigned short As[128*SD_];
  __shared__ __align__(16) unsigned short Bs[128*SD_];
  int tid = threadIdx.x, w = tid>>6, l = tid&63;
  int m0 = blockIdx.x*128, n0 = blockIdx.y*128;
  int wr = (w>>1)*64, wc = (w&1)*64;
  int lr = l&15, qd = l>>4;
  int srow = tid>>2, scol = (tid&3)*8;

  const f32x4 fz = {0.f,0.f,0.f,0.f};
  f32x4 acc[4][4];
  #pragma unroll
  for (int i=0;i<4;i++)
    #pragma unroll
    for (int j=0;j<4;j++) acc[i][j] = fz;

  for (int kk=0; kk<D_; kk+=32){
    __syncthreads();
    *(uint4*)(As + srow*SD_      + scol) = *(const uint4*)(A  + (size_t)(m0+srow   )*D_ + kk + scol);
    *(uint4*)(As + (srow+64)*SD_ + scol) = *(const uint4*)(A  + (size_t)(m0+srow+64)*D_ + kk + scol);
    *(uint4*)(Bs + srow*SD_      + scol) = *(const uint4*)(Bt + (size_t)(n0+srow   )*D_ + kk + scol);
    *(uint4*)(Bs + (srow+64)*SD_ + scol) = *(const uint4*)(Bt + (size_t)(n0+srow+64)*D_ + kk + scol);
    __syncthreads();
    short8 af[4], bfr[4];
    #pragma unroll
    for (int i=0;i<4;i++) af[i]  = *(const short8*)(As + (wr + i*16 + lr)*SD_ + qd*8);
    #pragma unroll
    for (int j=0;j<4;j++) bfr[j] = *(const short8*)(Bs + (wc + j*16 + lr)*SD_ + qd*8);
    #pragma unroll
    for (int i=0;i<4;i++)
      #pragma unroll
      for (int j=0;j<4;j++)
        acc[i][j] = __builtin_amdgcn_mfma_f32_16x16x32_bf16(af[i], bfr[j], acc[i][j], 0, 0, 0);
  }

  #pragma unroll
  for (int j=0;j<4;j++){
    int n = n0 + wc + j*16 + lr;
    float bias_n = bo[n];
    #pragma unroll
    for (int i=0;i<4;i++){
      int mb = m0 + wr + i*16 + qd*4;
      Cf[(size_t)(mb+0)*D_ + n] = acc[i][j][0] + bias_n;
      Cf[(size_t)(mb+1)*D_ + n] = acc[i][j][1] + bias_n;
      Cf[(size_t)(mb+2)*D_ + n] = acc[i][j][2] + bias_n;
      Cf[(size_t)(mb+3)*D_ + n] = acc[i][j][3] + bias_n;
    }
  }
}

// ---------------------------------------------------------------------------
// Fused double Hopfield attention, transposed compute (S^T/O^T), in-place on
// QO (bf16, CE-prescaled). 128 q-rows/block, 4 waves x 32 q (2 groups of 16),
// grid (32,16) = 512 blocks. Stride-56 LDS: conflict-free b128 reads.
//   phase 0: q2 = softmax(q K^T) K (via KT) ; phase 1: out = softmax(q2 K^T) V
// ---------------------------------------------------------------------------
__global__ __launch_bounds__(256) void attn_fused(
  unsigned short* __restrict__ QO,
  const unsigned short* __restrict__ K,
  const unsigned short* __restrict__ KT,
  const unsigned short* __restrict__ VT)
{
  int qt = blockIdx.x;           // 0..31 (128-row q tile)
  int h  = blockIdx.y;           // 0..15
  int b  = qt >> 4;
  int bh = b*H_ + h;
  int tid = threadIdx.x, w = tid>>6, l = tid&63;
  int lr = l&15, qd = l>>4;
  int r8 = tid>>3, c8 = (tid&7)*8;
  int chf = c8>>5, co = c8&31;

  __shared__ __align__(16) unsigned short sK[2][64*SD_];   // [d-half][key*SD + d%32]
  __shared__ __align__(16) unsigned short sV[2][64*SD_];   // [s-half][d*SD + s%32]
  __shared__ __align__(16) unsigned short sP[4][2][32*SD_];// per-wave [half][q*SD + off]

  const f32x4 fz = {0.f,0.f,0.f,0.f};

  // Q fragments (B-operand [q][d]) straight from global; CE prefolded.
  unsigned short* Qbase = QO + (size_t)(qt*128 + w*32) * D_ + h*64;
  short8 qf[2][2];
  #pragma unroll
  for (int gg=0; gg<2; gg++)
    #pragma unroll
    for (int hf=0; hf<2; hf++)
      qf[gg][hf] = *(const short8*)(Qbase + (size_t)(gg*16+lr)*D_ + hf*32 + qd*8);

  const unsigned short* Khead = K + (size_t)(b*S_)*D_ + h*64;
  unsigned short* Pw0 = &sP[w][0][0];
  unsigned short* Pw1 = &sP[w][1][0];

  f32x4 oacc[2][4];   // O^T: lane (d = dt*16+qd*4+r, q = gg*16+lr)
  float lac[2];

  #pragma unroll 1
  for (int phase=0; phase<2; phase++){
    const unsigned short* Vhead = (phase ? VT : KT) + (size_t)bh*HD_*S_;
    lac[0]=0.f; lac[1]=0.f;
    #pragma unroll
    for (int gg=0;gg<2;gg++)
      #pragma unroll
      for (int t=0;t<4;t++) oacc[gg][t]=fz;

    for (int kt=0; kt<S_; kt+=64){
      __syncthreads();
      *(uint4*)(&sK[chf][(r8   )*SD_ + co]) = *(const uint4*)(Khead + (size_t)(kt+r8   )*D_ + c8);
      *(uint4*)(&sK[chf][(r8+32)*SD_ + co]) = *(const uint4*)(Khead + (size_t)(kt+r8+32)*D_ + c8);
      *(uint4*)(&sV[chf][(r8   )*SD_ + co]) = *(const uint4*)(Vhead + (size_t)(r8   )*S_ + kt + c8);
      *(uint4*)(&sV[chf][(r8+32)*SD_ + co]) = *(const uint4*)(Vhead + (size_t)(r8+32)*S_ + kt + c8);
      __syncthreads();

      // S^T strip: 64 keys x 32 q per wave. A=K-frag, B=Q-frag.
      f32x4 sc[2][4];
      #pragma unroll
      for (int st=0; st<4; st++){
        short8 kA0 = *(const short8*)(&sK[0][(st*16+lr)*SD_ + qd*8]);
        short8 kA1 = *(const short8*)(&sK[1][(st*16+lr)*SD_ + qd*8]);
        #pragma unroll
        for (int gg=0; gg<2; gg++){
          f32x4 z = fz;
          z = __builtin_amdgcn_mfma_f32_16x16x32_bf16(kA0, qf[gg][0], z, 0,0,0);
          z = __builtin_amdgcn_mfma_f32_16x16x32_bf16(kA1, qf[gg][1], z, 0,0,0);
          sc[gg][st] = z;
        }
      }
      // exp2 + in-lane row-sum + packed b64 stores into sP[q][s]
      #pragma unroll
      for (int gg=0; gg<2; gg++)
        #pragma unroll
        for (int st=0; st<4; st++){
          float p0=exp2f(sc[gg][st][0]), p1=exp2f(sc[gg][st][1]);
          float p2=exp2f(sc[gg][st][2]), p3=exp2f(sc[gg][st][3]);
          lac[gg] += (p0+p1)+(p2+p3);
          uint2 pk; pk.x = pk2bft(p0,p1); pk.y = pk2bft(p2,p3);
          unsigned short* Ph = (st&2) ? Pw1 : Pw0;
          *(uint2*)(Ph + (gg*16+lr)*SD_ + (st&1)*16 + qd*4) = pk;
        }
      short8 pf[2][2];
      #pragma unroll
      for (int gg=0; gg<2; gg++){
        pf[gg][0] = *(const short8*)(Pw0 + (gg*16+lr)*SD_ + qd*8);
        pf[gg][1] = *(const short8*)(Pw1 + (gg*16+lr)*SD_ + qd*8);
      }
      // O^T += V^T-frag * P-frag
      #pragma unroll
      for (int dt=0; dt<4; dt++){
        short8 vA0 = *(const short8*)(&sV[0][(dt*16+lr)*SD_ + qd*8]);
        short8 vA1 = *(const short8*)(&sV[1][(dt*16+lr)*SD_ + qd*8]);
        #pragma unroll
        for (int gg=0; gg<2; gg++){
          oacc[gg][dt] = __builtin_amdgcn_mfma_f32_16x16x32_bf16(vA0, pf[gg][0], oacc[gg][dt], 0,0,0);
          oacc[gg][dt] = __builtin_amdgcn_mfma_f32_16x16x32_bf16(vA1, pf[gg][1], oacc[gg][dt], 0,0,0);
        }
      }
    } // kt

    // complete row-sums over the 4 quads
    #pragma unroll
    for (int gg=0;gg<2;gg++){
      lac[gg] += __shfl_xor(lac[gg], 16, 64);
      lac[gg] += __shfl_xor(lac[gg], 32, 64);
    }

    if (phase==0){
      // q2 = O^T/l * CE -> new Q fragments via sP[q][d]
      #pragma unroll
      for (int gg=0;gg<2;gg++){
        float iv = CE_ / lac[gg];
        #pragma unroll
        for (int dt=0;dt<4;dt++){
          uint2 pk;
          pk.x = pk2bf(oacc[gg][dt][0]*iv, oacc[gg][dt][1]*iv);
          pk.y = pk2bf(oacc[gg][dt][2]*iv, oacc[gg][dt][3]*iv);
          unsigned short* Ph = (dt&2) ? Pw1 : Pw0;
          *(uint2*)(Ph + (gg*16+lr)*SD_ + (dt&1)*16 + qd*4) = pk;
        }
      }
      #pragma unroll
      for (int gg=0;gg<2;gg++){
        qf[gg][0] = *(const short8*)(Pw0 + (gg*16+lr)*SD_ + qd*8);
        qf[gg][1] = *(const short8*)(Pw1 + (gg*16+lr)*SD_ + qd*8);
      }
    } else {
      #pragma unroll
      for (int gg=0;gg<2;gg++){
        float iv = 1.0f / lac[gg];
        unsigned short* Ob = QO + (size_t)(qt*128 + w*32 + gg*16 + lr)*D_ + h*64;
        #pragma unroll
        for (int dt=0;dt<4;dt++){
          uint2 pk;
          pk.x = pk2bf(oacc[gg][dt][0]*iv, oacc[gg][dt][1]*iv);
          pk.y = pk2bf(oacc[gg][dt][2]*iv, oacc[gg][dt][3]*iv);
          *(uint2*)(Ob + dt*16 + qd*4) = pk;
        }
      }
    }
  } // phase
}

// ---------------------------------------------------------------------------
extern "C" void kernel_launch(void* const* d_in, const int* in_sizes, int n_in,
                              void* d_out, int out_size, void* d_ws, size_t ws_size,
                              hipStream_t stream){
  const float* data = (const float*)d_in[0];
  const float* g_k  = (const float*)d_in[1];
  const float* b_k  = (const float*)d_in[2];
  const float* g_q  = (const float*)d_in[3];
  const float* b_q  = (const float*)d_in[4];
  const float* g_v  = (const float*)d_in[5];
  const float* b_v  = (const float*)d_in[6];
  const float* Wq   = (const float*)d_in[7];
  const float* bq   = (const float*)d_in[8];
  const float* Wk   = (const float*)d_in[9];
  const float* bk   = (const float*)d_in[10];
  const float* Wv   = (const float*)d_in[11];
  const float* bv   = (const float*)d_in[12];
  const float* Wo   = (const float*)d_in[13];
  const float* bo   = (const float*)d_in[14];
  float* out = (float*)d_out;

  char* ws = (char*)d_ws;
  const size_t MB = (size_t)1<<20;
  unsigned short* q    = (unsigned short*)(ws);           // ws[0,8) MB
  unsigned short* kb   = (unsigned short*)(ws + 8*MB);    // ws[8,16) MB
  unsigned short* WT   = (unsigned short*)(ws + 16*MB);   // ws[16,24) MB
  unsigned short* WTo  = WT + ((size_t)3<<20);
  float*          bfld = (float*)(ws + 24*MB);            // 3*1024 f32
  float*          mean = bfld + 3*D_;                     // 4096 f32
  float*          rstd = mean + M_;                       // 4096 f32
  unsigned short* vT   = (unsigned short*)d_out;                 // d_out[0,8) MB
  unsigned short* kT   = (unsigned short*)((char*)d_out + 8*MB); // d_out[8,16) MB

  dim3 gb(256);
  stats_kernel<<<dim3(M_/4), gb, 0, stream>>>(data, mean, rstd);
  biasfold_kernel<<<dim3(16,3), gb, 0, stream>>>(Wq,Wk,Wv, b_q,b_k,b_v, bq,bk,bv, bfld);
  wtrans_kernel<<<dim3(16,16,4), gb, 0, stream>>>(Wq,Wk,Wv,Wo, g_q,g_k,g_v, WT);
  gemm_qkv<<<dim3(32,8,3), gb, 0, stream>>>(data, WT, bfld, mean, rstd, q, kb, kT, vT);
  attn_fused<<<dim3(32, H_), gb, 0, stream>>>(q, kb, kT, vT);
  gemm_out<<<dim3(32,8), gb, 0, stream>>>(q, WTo, bo, out);
}

// Round 9
// 292.390 us; speedup vs baseline: 2.2802x; 1.1082x over previous
//
#include <hip/hip_runtime.h>
#include <hip/hip_bf16.h>

// Problem constants
#define B_  2
#define S_  2048
#define D_  1024
#define H_  16
#define HD_ 64
#define M_  4096   // B_*S_

// Inputs/outputs f32; internal compute bf16 MFMA with f32 accumulation.
//
// ws (24 MB + 45 KB):
//   [0,8)MB  q bf16 (CE-prescaled; attn in-place)
//   [8,16)MB kb bf16
//   [16,24)MB WT bf16: 4 x [1024][1024] ([q CE*g | k g | v g | o plain])
//   +24MB: biasf f32[3][1024], mean f32[4096], rstd f32[4096]
// d_out (16 MB f32) as scratch until the final GEMM:
//   [0,8)MB  vT bf16 [bh][d][s]     [8,16)MB kT bf16 [bh][d][s]
// gemm_out reads q + WT[o] (ws) and writes d_out directly (vT/kT dead).
// LDS row stride: 56 shorts (112B).

typedef __attribute__((ext_vector_type(8))) short short8;
typedef __attribute__((ext_vector_type(4))) float f32x4;

#define CE_ 0.1803368801111204f   // 0.125 * log2(e)
#define SD_ 56                    // LDS row stride in shorts

static __device__ __forceinline__ unsigned short f2bfc(float f){
  union{float f; unsigned u;} c; c.f = f;
  return (unsigned short)((c.u + 0x8000u) >> 16);       // round-half-up
}
static __device__ __forceinline__ unsigned pk2bf(float a, float b){
  union{float f; unsigned u;} ca, cb; ca.f=a; cb.f=b;
  return __builtin_amdgcn_perm(cb.u + 0x8000u, ca.u + 0x8000u, 0x07060302u);
}
static __device__ __forceinline__ unsigned pk2bft(float a, float b){
  union{float f; unsigned u;} ca, cb; ca.f=a; cb.f=b;
  return __builtin_amdgcn_perm(cb.u, ca.u, 0x07060302u);
}

// ---------------------------------------------------------------------------
// Per-row LN stats of data (f32): mean[row], rstd[row]. One wave per row.
// ---------------------------------------------------------------------------
__global__ __launch_bounds__(256) void stats_kernel(const float* __restrict__ x,
                                                    float* __restrict__ mean,
                                                    float* __restrict__ rstd){
  int row = blockIdx.x*4 + (threadIdx.x>>6);
  int l = threadIdx.x & 63;
  const float4* xr = (const float4*)(x + (size_t)row*D_);
  float s = 0.f, ss = 0.f;
  #pragma unroll
  for (int i=0;i<4;i++){
    float4 v = xr[l + 64*i];
    s  += v.x+v.y+v.z+v.w;
    ss += v.x*v.x+v.y*v.y+v.z*v.z+v.w*v.w;
  }
  #pragma unroll
  for (int m=1;m<64;m<<=1){ s += __shfl_xor(s, m, 64); ss += __shfl_xor(ss, m, 64); }
  if (l==0){
    float me = s*(1.0f/D_);
    float var = ss*(1.0f/D_) - me*me;
    mean[row] = me;
    rstd[row] = rsqrtf(var + 1e-5f);
  }
}

// ---------------------------------------------------------------------------
// Folded bias: biasf[z][n] = (bp_z[n] + sum_k bln_z[k]*W_z[k][n]) * (z==0?CE:1)
// ---------------------------------------------------------------------------
__global__ __launch_bounds__(256) void biasfold_kernel(
  const float* __restrict__ Wq, const float* __restrict__ Wk, const float* __restrict__ Wv,
  const float* __restrict__ blq, const float* __restrict__ blk, const float* __restrict__ blv,
  const float* __restrict__ bpq, const float* __restrict__ bpk, const float* __restrict__ bpv,
  float* __restrict__ bf){
  int z = blockIdx.y;
  const float* W  = (z==0)?Wq:(z==1)?Wk:Wv;
  const float* bl = (z==0)?blq:(z==1)?blk:blv;
  const float* bp = (z==0)?bpq:(z==1)?bpk:bpv;
  int nl = threadIdx.x & 63, kg = threadIdx.x >> 6;
  int n = blockIdx.x*64 + nl;
  float acc = 0.f;
  for (int k = kg*256; k < (kg+1)*256; k++)
    acc += bl[k] * W[(size_t)k*D_ + n];
  __shared__ float red[4][64];
  red[kg][nl] = acc;
  __syncthreads();
  if (threadIdx.x < 64){
    int nn = blockIdx.x*64 + threadIdx.x;
    float v = red[0][threadIdx.x]+red[1][threadIdx.x]+red[2][threadIdx.x]+red[3][threadIdx.x]
              + bp[nn];
    bf[z*D_ + nn] = (z==0) ? v*CE_ : v;
  }
}

// ---------------------------------------------------------------------------
// Weight transpose + cast: WT[z][n][k] = scale_z[k] * W_z[k][n]  (bf16 out)
// ---------------------------------------------------------------------------
__global__ __launch_bounds__(256) void wtrans_kernel(
  const float* __restrict__ Wq, const float* __restrict__ Wk,
  const float* __restrict__ Wv, const float* __restrict__ Wo,
  const float* __restrict__ gq, const float* __restrict__ gk,
  const float* __restrict__ gv,
  unsigned short* __restrict__ WT){
  int z = blockIdx.z;
  const float* W = (z==0)?Wq:(z==1)?Wk:(z==2)?Wv:Wo;
  const float* g = (z==0)?gq:(z==1)?gk:(z==2)?gv:(const float*)0;
  unsigned short* out = WT + ((size_t)z<<20);
  int k0 = blockIdx.x*64, n0 = blockIdx.y*64;
  __shared__ unsigned short tile[64][72];
  int t = threadIdx.x;
  {
    int kr = t>>2, c16 = (t&3)*16;
    float gs = g ? g[k0+kr]*((z==0)?CE_:1.0f) : 1.0f;
    const float* src = W + (size_t)(k0+kr)*D_ + n0 + c16;
    float4 w0 = *(const float4*)(src);
    float4 w1 = *(const float4*)(src+4);
    float4 w2 = *(const float4*)(src+8);
    float4 w3 = *(const float4*)(src+12);
    unsigned* tp = (unsigned*)&tile[kr][c16];
    tp[0]=pk2bf(w0.x*gs,w0.y*gs); tp[1]=pk2bf(w0.z*gs,w0.w*gs);
    tp[2]=pk2bf(w1.x*gs,w1.y*gs); tp[3]=pk2bf(w1.z*gs,w1.w*gs);
    tp[4]=pk2bf(w2.x*gs,w2.y*gs); tp[5]=pk2bf(w2.z*gs,w2.w*gs);
    tp[6]=pk2bf(w3.x*gs,w3.y*gs); tp[7]=pk2bf(w3.z*gs,w3.w*gs);
  }
  __syncthreads();
  {
    int nr = t>>2, kc = (t&3)*16;
    union { uint4 v[2]; unsigned short u[16]; } st;
    #pragma unroll
    for (int i=0;i<16;i++) st.u[i] = tile[kc+i][nr];
    unsigned short* dst = out + (size_t)(n0+nr)*D_ + k0 + kc;
    *(uint4*)(dst)     = st.v[0];
    *(uint4*)(dst + 8) = st.v[1];
  }
}

// ---------------------------------------------------------------------------
// Fused QKV GEMM, grid (32,8,3). 128x128 tile, 4 waves, stride-56 LDS.
// ---------------------------------------------------------------------------
__global__ __launch_bounds__(256) void gemm_qkv(
  const float* __restrict__ data,
  const unsigned short* __restrict__ WT,
  const float* __restrict__ biasf,
  const float* __restrict__ mean, const float* __restrict__ rstd,
  unsigned short* __restrict__ qv, unsigned short* __restrict__ kb,
  unsigned short* __restrict__ kT, unsigned short* __restrict__ vT)
{
  int z = blockIdx.z;
  const unsigned short* Bt = WT + ((size_t)z<<20);
  const float* bias = biasf + z*D_;
  unsigned short* oN = (z==0)?qv:(z==1)?kb:(unsigned short*)0;
  unsigned short* oT = (z==0)?(unsigned short*)0:(z==1)?kT:vT;

  __shared__ __align__(16) unsigned short As[128*SD_];
  __shared__ __align__(16) unsigned short Bs[128*SD_];
  int tid = threadIdx.x, w = tid>>6, l = tid&63;
  int m0 = blockIdx.x*128, n0 = blockIdx.y*128;
  int wr = (w>>1)*64, wc = (w&1)*64;
  int lr = l&15, qd = l>>4;
  int srow = tid>>2, scol = (tid&3)*8;

  float rs0 = rstd[m0+srow],    nm0 = -mean[m0+srow]*rs0;     // x*rs+nm = (x-me)*rs
  float rs1 = rstd[m0+srow+64], nm1 = -mean[m0+srow+64]*rs1;

  const f32x4 fz = {0.f,0.f,0.f,0.f};
  f32x4 acc[4][4];
  #pragma unroll
  for (int i=0;i<4;i++)
    #pragma unroll
    for (int j=0;j<4;j++) acc[i][j] = fz;

  for (int kk=0; kk<D_; kk+=32){
    __syncthreads();
    {
      const float* p0 = data + (size_t)(m0+srow   )*D_ + kk + scol;
      const float* p1 = data + (size_t)(m0+srow+64)*D_ + kk + scol;
      float4 a0 = *(const float4*)(p0), a0b = *(const float4*)(p0+4);
      float4 a1 = *(const float4*)(p1), a1b = *(const float4*)(p1+4);
      uint4 o0, o1;
      o0.x = pk2bf(fmaf(a0.x ,rs0,nm0), fmaf(a0.y ,rs0,nm0));
      o0.y = pk2bf(fmaf(a0.z ,rs0,nm0), fmaf(a0.w ,rs0,nm0));
      o0.z = pk2bf(fmaf(a0b.x,rs0,nm0), fmaf(a0b.y,rs0,nm0));
      o0.w = pk2bf(fmaf(a0b.z,rs0,nm0), fmaf(a0b.w,rs0,nm0));
      o1.x = pk2bf(fmaf(a1.x ,rs1,nm1), fmaf(a1.y ,rs1,nm1));
      o1.y = pk2bf(fmaf(a1.z ,rs1,nm1), fmaf(a1.w ,rs1,nm1));
      o1.z = pk2bf(fmaf(a1b.x,rs1,nm1), fmaf(a1b.y,rs1,nm1));
      o1.w = pk2bf(fmaf(a1b.z,rs1,nm1), fmaf(a1b.w,rs1,nm1));
      *(uint4*)(As + srow*SD_      + scol) = o0;
      *(uint4*)(As + (srow+64)*SD_ + scol) = o1;
    }
    *(uint4*)(Bs + srow*SD_      + scol) = *(const uint4*)(Bt + (size_t)(n0+srow   )*D_ + kk + scol);
    *(uint4*)(Bs + (srow+64)*SD_ + scol) = *(const uint4*)(Bt + (size_t)(n0+srow+64)*D_ + kk + scol);
    __syncthreads();
    short8 af[4], bfr[4];
    #pragma unroll
    for (int i=0;i<4;i++) af[i]  = *(const short8*)(As + (wr + i*16 + lr)*SD_ + qd*8);
    #pragma unroll
    for (int j=0;j<4;j++) bfr[j] = *(const short8*)(Bs + (wc + j*16 + lr)*SD_ + qd*8);
    #pragma unroll
    for (int i=0;i<4;i++)
      #pragma unroll
      for (int j=0;j<4;j++)
        acc[i][j] = __builtin_amdgcn_mfma_f32_16x16x32_bf16(af[i], bfr[j], acc[i][j], 0, 0, 0);
  }

  #pragma unroll
  for (int j=0;j<4;j++){
    int n = n0 + wc + j*16 + lr;
    float bias_n = bias[n];
    #pragma unroll
    for (int i=0;i<4;i++){
      int mb = m0 + wr + i*16 + qd*4;
      float v0 = acc[i][j][0] + bias_n;
      float v1 = acc[i][j][1] + bias_n;
      float v2 = acc[i][j][2] + bias_n;
      float v3 = acc[i][j][3] + bias_n;
      if (oN){
        oN[(size_t)(mb+0)*D_ + n] = f2bfc(v0);
        oN[(size_t)(mb+1)*D_ + n] = f2bfc(v1);
        oN[(size_t)(mb+2)*D_ + n] = f2bfc(v2);
        oN[(size_t)(mb+3)*D_ + n] = f2bfc(v3);
      }
      if (oT){
        int bb = mb >> 11, sI = mb & (S_-1);
        int hh = n >> 6,  dd = n & 63;
        uint2 pk; pk.x = pk2bf(v0, v1); pk.y = pk2bf(v2, v3);
        *(uint2*)(oT + (size_t)((bb*H_ + hh)*HD_ + dd)*S_ + sI) = pk;
      }
    }
  }
}

// ---------------------------------------------------------------------------
// Out-projection: C = A(bf16) @ WTo^T + bo, f32 straight to d_out.
// ---------------------------------------------------------------------------
__global__ __launch_bounds__(256) void gemm_out(
  const unsigned short* __restrict__ A,
  const unsigned short* __restrict__ Bt,
  const float* __restrict__ bo,
  float* __restrict__ Cf)
{
  __shared__ __align__(16) unsigned short As[128*SD_];
  __shared__ __align__(16) unsigned short Bs[128*SD_];
  int tid = threadIdx.x, w = tid>>6, l = tid&63;
  int m0 = blockIdx.x*128, n0 = blockIdx.y*128;
  int wr = (w>>1)*64, wc = (w&1)*64;
  int lr = l&15, qd = l>>4;
  int srow = tid>>2, scol = (tid&3)*8;

  const f32x4 fz = {0.f,0.f,0.f,0.f};
  f32x4 acc[4][4];
  #pragma unroll
  for (int i=0;i<4;i++)
    #pragma unroll
    for (int j=0;j<4;j++) acc[i][j] = fz;

  for (int kk=0; kk<D_; kk+=32){
    __syncthreads();
    *(uint4*)(As + srow*SD_      + scol) = *(const uint4*)(A  + (size_t)(m0+srow   )*D_ + kk + scol);
    *(uint4*)(As + (srow+64)*SD_ + scol) = *(const uint4*)(A  + (size_t)(m0+srow+64)*D_ + kk + scol);
    *(uint4*)(Bs + srow*SD_      + scol) = *(const uint4*)(Bt + (size_t)(n0+srow   )*D_ + kk + scol);
    *(uint4*)(Bs + (srow+64)*SD_ + scol) = *(const uint4*)(Bt + (size_t)(n0+srow+64)*D_ + kk + scol);
    __syncthreads();
    short8 af[4], bfr[4];
    #pragma unroll
    for (int i=0;i<4;i++) af[i]  = *(const short8*)(As + (wr + i*16 + lr)*SD_ + qd*8);
    #pragma unroll
    for (int j=0;j<4;j++) bfr[j] = *(const short8*)(Bs + (wc + j*16 + lr)*SD_ + qd*8);
    #pragma unroll
    for (int i=0;i<4;i++)
      #pragma unroll
      for (int j=0;j<4;j++)
        acc[i][j] = __builtin_amdgcn_mfma_f32_16x16x32_bf16(af[i], bfr[j], acc[i][j], 0, 0, 0);
  }

  #pragma unroll
  for (int j=0;j<4;j++){
    int n = n0 + wc + j*16 + lr;
    float bias_n = bo[n];
    #pragma unroll
    for (int i=0;i<4;i++){
      int mb = m0 + wr + i*16 + qd*4;
      Cf[(size_t)(mb+0)*D_ + n] = acc[i][j][0] + bias_n;
      Cf[(size_t)(mb+1)*D_ + n] = acc[i][j][1] + bias_n;
      Cf[(size_t)(mb+2)*D_ + n] = acc[i][j][2] + bias_n;
      Cf[(size_t)(mb+3)*D_ + n] = acc[i][j][3] + bias_n;
    }
  }
}

// ---------------------------------------------------------------------------
// Fused double Hopfield attention, transposed compute (S^T/O^T), in-place on
// QO (bf16, CE-prescaled). 128 q/block, 4 waves x 32 q, grid (32,16).
// HW exp2 (__builtin_amdgcn_exp2f) + register-prefetch staging pipeline.
// ---------------------------------------------------------------------------
__global__ __launch_bounds__(256) void attn_fused(
  unsigned short* __restrict__ QO,
  const unsigned short* __restrict__ K,
  const unsigned short* __restrict__ KT,
  const unsigned short* __restrict__ VT)
{
  int qt = blockIdx.x;           // 0..31
  int h  = blockIdx.y;           // 0..15
  int b  = qt >> 4;
  int bh = b*H_ + h;
  int tid = threadIdx.x, w = tid>>6, l = tid&63;
  int lr = l&15, qd = l>>4;
  int r8 = tid>>3, c8 = (tid&7)*8;
  int chf = c8>>5, co = c8&31;

  __shared__ __align__(16) unsigned short sK[2][64*SD_];
  __shared__ __align__(16) unsigned short sV[2][64*SD_];
  __shared__ __align__(16) unsigned short sP[4][2][32*SD_];

  const f32x4 fz = {0.f,0.f,0.f,0.f};

  unsigned short* Qbase = QO + (size_t)(qt*128 + w*32) * D_ + h*64;
  short8 qf[2][2];
  #pragma unroll
  for (int gg=0; gg<2; gg++)
    #pragma unroll
    for (int hf=0; hf<2; hf++)
      qf[gg][hf] = *(const short8*)(Qbase + (size_t)(gg*16+lr)*D_ + hf*32 + qd*8);

  const unsigned short* Khead = K + (size_t)(b*S_)*D_ + h*64;
  const unsigned short* Vh0 = KT + (size_t)bh*HD_*S_;
  const unsigned short* Vh1 = VT + (size_t)bh*HD_*S_;
  unsigned short* Pw0 = &sP[w][0][0];
  unsigned short* Pw1 = &sP[w][1][0];

  f32x4 oacc[2][4];
  float lac[2];

  // staging registers (software pipeline)
  uint4 kr0, kr1, vr0, vr1;
  {
    kr0 = *(const uint4*)(Khead + (size_t)(r8   )*D_ + c8);
    kr1 = *(const uint4*)(Khead + (size_t)(r8+32)*D_ + c8);
    vr0 = *(const uint4*)(Vh0 + (size_t)(r8   )*S_ + c8);
    vr1 = *(const uint4*)(Vh0 + (size_t)(r8+32)*S_ + c8);
  }

  #pragma unroll 1
  for (int phase=0; phase<2; phase++){
    const unsigned short* Vhead = phase ? Vh1 : Vh0;
    lac[0]=0.f; lac[1]=0.f;
    #pragma unroll
    for (int gg=0;gg<2;gg++)
      #pragma unroll
      for (int t=0;t<4;t++) oacc[gg][t]=fz;

    for (int kt=0; kt<S_; kt+=64){
      __syncthreads();
      *(uint4*)(&sK[chf][(r8   )*SD_ + co]) = kr0;
      *(uint4*)(&sK[chf][(r8+32)*SD_ + co]) = kr1;
      *(uint4*)(&sV[chf][(r8   )*SD_ + co]) = vr0;
      *(uint4*)(&sV[chf][(r8+32)*SD_ + co]) = vr1;
      __syncthreads();

      // prefetch next tile (next kt, or next phase's kt=0)
      {
        int nkt = kt + 64;
        const unsigned short* Vn = Vhead;
        if (nkt >= S_){ nkt = 0; Vn = Vh1; }   // phase 1 end: harmless re-read
        kr0 = *(const uint4*)(Khead + (size_t)(nkt+r8   )*D_ + c8);
        kr1 = *(const uint4*)(Khead + (size_t)(nkt+r8+32)*D_ + c8);
        vr0 = *(const uint4*)(Vn + (size_t)(r8   )*S_ + nkt + c8);
        vr1 = *(const uint4*)(Vn + (size_t)(r8+32)*S_ + nkt + c8);
      }

      // S^T strip: 64 keys x 32 q per wave. A=K-frag, B=Q-frag.
      f32x4 sc[2][4];
      #pragma unroll
      for (int st=0; st<4; st++){
        short8 kA0 = *(const short8*)(&sK[0][(st*16+lr)*SD_ + qd*8]);
        short8 kA1 = *(const short8*)(&sK[1][(st*16+lr)*SD_ + qd*8]);
        #pragma unroll
        for (int gg=0; gg<2; gg++){
          f32x4 z = fz;
          z = __builtin_amdgcn_mfma_f32_16x16x32_bf16(kA0, qf[gg][0], z, 0,0,0);
          z = __builtin_amdgcn_mfma_f32_16x16x32_bf16(kA1, qf[gg][1], z, 0,0,0);
          sc[gg][st] = z;
        }
      }
      // HW exp2 + in-lane row-sum + packed b64 stores into sP[q][s]
      #pragma unroll
      for (int gg=0; gg<2; gg++)
        #pragma unroll
        for (int st=0; st<4; st++){
          float p0=__builtin_amdgcn_exp2f(sc[gg][st][0]);
          float p1=__builtin_amdgcn_exp2f(sc[gg][st][1]);
          float p2=__builtin_amdgcn_exp2f(sc[gg][st][2]);
          float p3=__builtin_amdgcn_exp2f(sc[gg][st][3]);
          lac[gg] += (p0+p1)+(p2+p3);
          uint2 pk; pk.x = pk2bft(p0,p1); pk.y = pk2bft(p2,p3);
          unsigned short* Ph = (st&2) ? Pw1 : Pw0;
          *(uint2*)(Ph + (gg*16+lr)*SD_ + (st&1)*16 + qd*4) = pk;
        }
      short8 pf[2][2];
      #pragma unroll
      for (int gg=0; gg<2; gg++){
        pf[gg][0] = *(const short8*)(Pw0 + (gg*16+lr)*SD_ + qd*8);
        pf[gg][1] = *(const short8*)(Pw1 + (gg*16+lr)*SD_ + qd*8);
      }
      // O^T += V^T-frag * P-frag
      #pragma unroll
      for (int dt=0; dt<4; dt++){
        short8 vA0 = *(const short8*)(&sV[0][(dt*16+lr)*SD_ + qd*8]);
        short8 vA1 = *(const short8*)(&sV[1][(dt*16+lr)*SD_ + qd*8]);
        #pragma unroll
        for (int gg=0; gg<2; gg++){
          oacc[gg][dt] = __builtin_amdgcn_mfma_f32_16x16x32_bf16(vA0, pf[gg][0], oacc[gg][dt], 0,0,0);
          oacc[gg][dt] = __builtin_amdgcn_mfma_f32_16x16x32_bf16(vA1, pf[gg][1], oacc[gg][dt], 0,0,0);
        }
      }
    } // kt

    #pragma unroll
    for (int gg=0;gg<2;gg++){
      lac[gg] += __shfl_xor(lac[gg], 16, 64);
      lac[gg] += __shfl_xor(lac[gg], 32, 64);
    }

    if (phase==0){
      #pragma unroll
      for (int gg=0;gg<2;gg++){
        float iv = CE_ * __builtin_amdgcn_rcpf(lac[gg]);
        #pragma unroll
        for (int dt=0;dt<4;dt++){
          uint2 pk;
          pk.x = pk2bf(oacc[gg][dt][0]*iv, oacc[gg][dt][1]*iv);
          pk.y = pk2bf(oacc[gg][dt][2]*iv, oacc[gg][dt][3]*iv);
          unsigned short* Ph = (dt&2) ? Pw1 : Pw0;
          *(uint2*)(Ph + (gg*16+lr)*SD_ + (dt&1)*16 + qd*4) = pk;
        }
      }
      __builtin_amdgcn_s_waitcnt(0);  // lgkm drain before re-read (wave-private region)
      #pragma unroll
      for (int gg=0;gg<2;gg++){
        qf[gg][0] = *(const short8*)(Pw0 + (gg*16+lr)*SD_ + qd*8);
        qf[gg][1] = *(const short8*)(Pw1 + (gg*16+lr)*SD_ + qd*8);
      }
    } else {
      #pragma unroll
      for (int gg=0;gg<2;gg++){
        float iv = __builtin_amdgcn_rcpf(lac[gg]);
        unsigned short* Ob = QO + (size_t)(qt*128 + w*32 + gg*16 + lr)*D_ + h*64;
        #pragma unroll
        for (int dt=0;dt<4;dt++){
          uint2 pk;
          pk.x = pk2bf(oacc[gg][dt][0]*iv, oacc[gg][dt][1]*iv);
          pk.y = pk2bf(oacc[gg][dt][2]*iv, oacc[gg][dt][3]*iv);
          *(uint2*)(Ob + dt*16 + qd*4) = pk;
        }
      }
    }
  } // phase
}

// ---------------------------------------------------------------------------
extern "C" void kernel_launch(void* const* d_in, const int* in_sizes, int n_in,
                              void* d_out, int out_size, void* d_ws, size_t ws_size,
                              hipStream_t stream){
  const float* data = (const float*)d_in[0];
  const float* g_k  = (const float*)d_in[1];
  const float* b_k  = (const float*)d_in[2];
  const float* g_q  = (const float*)d_in[3];
  const float* b_q  = (const float*)d_in[4];
  const float* g_v  = (const float*)d_in[5];
  const float* b_v  = (const float*)d_in[6];
  const float* Wq   = (const float*)d_in[7];
  const float* bq   = (const float*)d_in[8];
  const float* Wk   = (const float*)d_in[9];
  const float* bk   = (const float*)d_in[10];
  const float* Wv   = (const float*)d_in[11];
  const float* bv   = (const float*)d_in[12];
  const float* Wo   = (const float*)d_in[13];
  const float* bo   = (const float*)d_in[14];
  float* out = (float*)d_out;

  char* ws = (char*)d_ws;
  const size_t MB = (size_t)1<<20;
  unsigned short* q    = (unsigned short*)(ws);           // ws[0,8) MB
  unsigned short* kb   = (unsigned short*)(ws + 8*MB);    // ws[8,16) MB
  unsigned short* WT   = (unsigned short*)(ws + 16*MB);   // ws[16,24) MB
  unsigned short* WTo  = WT + ((size_t)3<<20);
  float*          bfld = (float*)(ws + 24*MB);
  float*          mean = bfld + 3*D_;
  float*          rstd = mean + M_;
  unsigned short* vT   = (unsigned short*)d_out;                 // d_out[0,8) MB
  unsigned short* kT   = (unsigned short*)((char*)d_out + 8*MB); // d_out[8,16) MB

  dim3 gb(256);
  stats_kernel<<<dim3(M_/4), gb, 0, stream>>>(data, mean, rstd);
  biasfold_kernel<<<dim3(16,3), gb, 0, stream>>>(Wq,Wk,Wv, b_q,b_k,b_v, bq,bk,bv, bfld);
  wtrans_kernel<<<dim3(16,16,4), gb, 0, stream>>>(Wq,Wk,Wv,Wo, g_q,g_k,g_v, WT);
  gemm_qkv<<<dim3(32,8,3), gb, 0, stream>>>(data, WT, bfld, mean, rstd, q, kb, kT, vT);
  attn_fused<<<dim3(32, H_), gb, 0, stream>>>(q, kb, kT, vT);
  gemm_out<<<dim3(32,8), gb, 0, stream>>>(q, WTo, bo, out);
}